// Round 6
// baseline (172.679 us; speedup 1.0000x reference)
//
#include <hip/hip_runtime.h>
#include <math.h>

#define BB 32
#define WW 100
#define FF 128
#define KS 7
#define ET 256   // 2F (temporal GAT embed)
#define EF 200   // 2W (feature GAT embed)

// ---------------- workspace layout (floats) ----------------
// x2:   409600   409600   conv output (B,W,F)
// x3T:  819200   409600   temporal GAT output, TRANSPOSED (B,F,W)
// LT:   1228800  819200   temporal left TRANSPOSED (B,256,100) -> reused LfT (B,200,128)
// Rt:   2048000  819200   temporal right TRANSPOSED (B,256,100) -> reused RfT (B,200,128)
// tj:   2867200  4096     tj[b][j] = sum_w fcw[w]*x4[b,w,j]
// wt:   3297280  114688   conv weights transposed (I,K,O)
// tlwT: 3411968  65536    temp_lin_w transposed (256,256)
// flwT: 3477504  40000    feat_lin_w transposed (200,200)

// K0: transpose the three weight tensors
__global__ void k_prep(const float* __restrict__ cw, const float* __restrict__ tlw,
                       const float* __restrict__ flw, float* __restrict__ wt,
                       float* __restrict__ tlwT, float* __restrict__ flwT) {
    int id = blockIdx.x * 256 + threadIdx.x;
    if (id < KS * FF * FF) {
        // wt[i][k][o] = cw[o][i][k]
        int o = id & (FF - 1);
        int r = id >> 7;
        int k = r % KS;
        int i = r / KS;
        wt[id] = cw[(o * FF + i) * KS + k];
    }
    if (id < ET * ET) {
        int e = id & (ET - 1);
        int d = id >> 8;
        tlwT[id] = tlw[e * ET + d];
    }
    if (id < EF * EF) {
        int e = id % EF;
        int d = id / EF;
        flwT[id] = flw[e * EF + d];
    }
}

// K1: Conv1d 'same' + relu, pos-encode fused into staging.
// 512 thr = (o:128) x (i-quarter h:4). TW=10, grid = 32b x 10 tiles.
// xs[f][r] transposed LDS tile: compute reads are uniform broadcasts (b128).
#define CTW 10
#define NROW 16            // CTW + KS - 1
#define XPAD 20            // row stride: 80B -> 16B-aligned float4 rows
__global__ __launch_bounds__(512) void k_conv(const float* __restrict__ x,
                                              const float* __restrict__ wt,
                                              const float* __restrict__ cb,
                                              float* __restrict__ x2) {
    int tile = blockIdx.x % 10;
    int b = blockIdx.x / 10;
    int w0 = tile * CTW;
    int tid = threadIdx.x;
    int o = tid & (FF - 1);
    int h = tid >> 7;   // 0..3, i-quarter, wave-uniform
    __shared__ float xs[FF][XPAD];
    __shared__ float part[4][CTW][FF];
    for (int idx = tid; idx < NROW * FF; idx += 512) {
        int r = idx >> 7, f = idx & (FF - 1);
        int t = w0 - 3 + r;
        float v = 0.f;
        if ((unsigned)t < WW) {
            float div = __expf((float)f * (-9.210340371976184f / (float)FF));
            float arg = (float)t * div;
            v = x[(b * WW + t) * FF + f] + __sinf(arg) + __cosf(arg);
        }
        xs[f][r] = v;
    }
    __syncthreads();
    float acc[CTW];
#pragma unroll
    for (int t = 0; t < CTW; ++t) acc[t] = 0.f;
    const float* wbase = wt + (h * 32) * KS * FF + o;
#pragma unroll 2
    for (int il = 0; il < 32; ++il) {
        int i = h * 32 + il;
        float4 X0 = *(const float4*)&xs[i][0];
        float4 X1 = *(const float4*)&xs[i][4];
        float4 X2 = *(const float4*)&xs[i][8];
        float4 X3 = *(const float4*)&xs[i][12];
        float xr[16] = {X0.x, X0.y, X0.z, X0.w, X1.x, X1.y, X1.z, X1.w,
                        X2.x, X2.y, X2.z, X2.w, X3.x, X3.y, X3.z, X3.w};
        const float* wp = wbase + il * KS * FF;
#pragma unroll
        for (int k = 0; k < KS; ++k) {
            float wv = wp[k * FF];
#pragma unroll
            for (int t = 0; t < CTW; ++t) acc[t] += xr[t + k] * wv;
        }
    }
#pragma unroll
    for (int t = 0; t < CTW; ++t) part[h][t][o] = acc[t];
    __syncthreads();
    for (int idx = tid; idx < CTW * FF; idx += 512) {
        int t = idx >> 7, oo = idx & (FF - 1);
        float s = part[0][t][oo] + part[1][t][oo] + part[2][t][oo] +
                  part[3][t][oo] + cb[oo];
        x2[(b * WW + w0 + t) * FF + oo] = fmaxf(s, 0.f);
    }
}

// K2: temporal L/R GEMM. 512 thr = (e:256) x (row-half rh:2), 8 rows/block.
// x rows staged in LDS (broadcast reads). Outputs TRANSPOSED: LT/Rt (B,256,100).
__global__ __launch_bounds__(512) void k_lr_t(const float* __restrict__ x2,
                                              const float* __restrict__ tlwT,
                                              const float* __restrict__ tlb,
                                              float* __restrict__ LT,
                                              float* __restrict__ Rt) {
    int tile = blockIdx.x % 13;
    int b = blockIdx.x / 13;
    int i0 = tile * 8;
    int tid = threadIdx.x;
    int e = tid & 255;
    int rh = tid >> 8;
    __shared__ float xs[8][FF];
    for (int idx = tid; idx < 8 * FF; idx += 512) {
        int r = idx >> 7, d = idx & (FF - 1);
        int row = i0 + r; if (row >= WW) row = WW - 1;  // clamp (never stored)
        xs[r][d] = x2[(b * WW + row) * FF + d];
    }
    __syncthreads();
    float aL[4] = {0, 0, 0, 0}, aR[4] = {0, 0, 0, 0};
    const float* wl = tlwT + e;
#pragma unroll 2
    for (int dc = 0; dc < 32; ++dc) {
        float xv[4][4];
#pragma unroll
        for (int r = 0; r < 4; ++r)
            *(float4*)xv[r] = *(const float4*)&xs[rh * 4 + r][dc * 4];
#pragma unroll
        for (int q = 0; q < 4; ++q) {
            int d = dc * 4 + q;
            float wL = wl[d * ET];
            float wR = wl[(FF + d) * ET];
#pragma unroll
            for (int r = 0; r < 4; ++r) {
                aL[r] += xv[r][q] * wL;
                aR[r] += xv[r][q] * wR;
            }
        }
    }
    int ibase = i0 + rh * 4;
    if (ibase < WW) {
        float lb = tlb[e];
        float o0[4];
#pragma unroll
        for (int r = 0; r < 4; ++r) o0[r] = aL[r] + lb;
        *(float4*)&LT[(b * ET + e) * WW + ibase] = *(float4*)o0;
        *(float4*)&Rt[(b * ET + e) * WW + ibase] = *(float4*)aR;
    }
}

// K3: temporal attention, QT=4 queries/block (25 tiles, exact).
// 256 thr = j(128) x q(2); each thread scores 2 queries.
__global__ __launch_bounds__(256) void k_att_t(const float* __restrict__ LT,
                                               const float* __restrict__ Rt,
                                               const float* __restrict__ ta,
                                               const float* __restrict__ tbias,
                                               const float* __restrict__ x2,
                                               float* __restrict__ x3T) {
    int tile = blockIdx.x % 25;
    int b = blockIdx.x / 25;
    int i0 = tile * 4;
    int tid = threadIdx.x;
    int j = tid & 127, q = tid >> 7;
    const float* Lb = LT + (b * ET) * WW + i0 + q * 2;
    const float* Rb = Rt + (b * ET) * WW;
    float s0 = 0.f, s1 = 0.f;
    for (int e = 0; e < ET; ++e) {
        float rj = Rb[e * WW + j];
        float2 lv = *(const float2*)&Lb[e * WW];
        float ae = ta[e];
        float v;
        v = lv.x + rj; v = fmaxf(v, 0.2f * v); s0 += v * ae;
        v = lv.y + rj; v = fmaxf(v, 0.2f * v); s1 += v * ae;
    }
    float ej[2] = {s0, s1};
#pragma unroll
    for (int ii = 0; ii < 2; ++ii) {
        int i = i0 + q * 2 + ii;
        ej[ii] = (j < WW) ? ej[ii] + tbias[i * WW + j] : -1e30f;
    }
    __shared__ float redA[4][2], redB[4][2];
    float m[2] = {ej[0], ej[1]};
#pragma unroll
    for (int off = 32; off > 0; off >>= 1) {
#pragma unroll
        for (int ii = 0; ii < 2; ++ii) m[ii] = fmaxf(m[ii], __shfl_xor(m[ii], off));
    }
    int wv = tid >> 6;
    if ((tid & 63) == 0) { redA[wv][0] = m[0]; redA[wv][1] = m[1]; }
    __syncthreads();
    float p[2], ps[2];
#pragma unroll
    for (int ii = 0; ii < 2; ++ii) {
        float mx = fmaxf(redA[wv][ii], redA[wv ^ 1][ii]);
        p[ii] = (j < WW) ? __expf(ej[ii] - mx) : 0.f;
        ps[ii] = p[ii];
    }
#pragma unroll
    for (int off = 32; off > 0; off >>= 1) {
#pragma unroll
        for (int ii = 0; ii < 2; ++ii) ps[ii] += __shfl_xor(ps[ii], off);
    }
    if ((tid & 63) == 0) { redB[wv][0] = ps[0]; redB[wv][1] = ps[1]; }
    __syncthreads();
    __shared__ float attQ[4][WW];   // [query][j]: writes lane-consecutive
    if (j < WW) {
#pragma unroll
        for (int ii = 0; ii < 2; ++ii) {
            float inv = 1.f / (redB[wv][ii] + redB[wv ^ 1][ii]);
            attQ[q * 2 + ii][j] = p[ii] * inv;
        }
    }
    __syncthreads();
    // PV: threads = d(128) x ph(2), 2 queries each
    int d = tid & 127, ph = tid >> 7;
    float pv0 = 0.f, pv1 = 0.f;
    const float* a0 = attQ[ph * 2];
    const float* a1 = attQ[ph * 2 + 1];
    for (int jj = 0; jj < WW; ++jj) {
        float xv = x2[(b * WW + jj) * FF + d];
        pv0 += a0[jj] * xv;
        pv1 += a1[jj] * xv;
    }
    __shared__ float ob[4][FF];     // [query][d]: conflict-free both ways
    ob[ph * 2][d] = tanhf(pv0);
    ob[ph * 2 + 1][d] = tanhf(pv1);
    __syncthreads();
    if (tid < FF) {
        float4 v = make_float4(ob[0][tid], ob[1][tid], ob[2][tid], ob[3][tid]);
        *(float4*)&x3T[(b * FF + tid) * WW + i0] = v;
    }
}

// K4: feature L/R GEMM. 512 thr = (e:256, valid<200) x (rh:2), 8 f-rows/block.
__global__ __launch_bounds__(512) void k_lr_f(const float* __restrict__ x3T,
                                              const float* __restrict__ flwT,
                                              const float* __restrict__ flb,
                                              float* __restrict__ LfT,
                                              float* __restrict__ RfT) {
    int tile = blockIdx.x & 15;
    int b = blockIdx.x >> 4;
    int f0 = tile * 8;
    int tid = threadIdx.x;
    int e = tid & 255;
    int rh = tid >> 8;
    __shared__ float xs[8][WW];
    for (int idx = tid; idx < 8 * WW; idx += 512) {
        int r = idx / WW, d = idx % WW;
        xs[r][d] = x3T[(b * FF + f0 + r) * WW + d];
    }
    __syncthreads();
    if (e < EF) {
        float aL[4] = {0, 0, 0, 0}, aR[4] = {0, 0, 0, 0};
        const float* wl = flwT + e;
#pragma unroll 2
        for (int dc = 0; dc < 25; ++dc) {
            float xv[4][4];
#pragma unroll
            for (int r = 0; r < 4; ++r)
                *(float4*)xv[r] = *(const float4*)&xs[rh * 4 + r][dc * 4];
#pragma unroll
            for (int q = 0; q < 4; ++q) {
                int d = dc * 4 + q;
                float wL = wl[d * EF];
                float wR = wl[(WW + d) * EF];
#pragma unroll
                for (int r = 0; r < 4; ++r) {
                    aL[r] += xv[r][q] * wL;
                    aR[r] += xv[r][q] * wR;
                }
            }
        }
        float lb = flb[e];
        float o0[4];
#pragma unroll
        for (int r = 0; r < 4; ++r) o0[r] = aL[r] + lb;
        int fbase = f0 + rh * 4;
        *(float4*)&LfT[(b * EF + e) * FF + fbase] = *(float4*)o0;
        *(float4*)&RfT[(b * EF + e) * FF + fbase] = *(float4*)aR;
    }
}

// K5: feature attention, QT=4 (32 tiles) + fused tj reduction.
__global__ __launch_bounds__(256) void k_att_f(const float* __restrict__ LfT,
                                               const float* __restrict__ RfT,
                                               const float* __restrict__ fa,
                                               const float* __restrict__ fbias,
                                               const float* __restrict__ x3T,
                                               const float* __restrict__ fcw,
                                               float* __restrict__ tj) {
    int tile = blockIdx.x & 31;
    int b = blockIdx.x >> 5;
    int f0 = tile * 4;
    int tid = threadIdx.x;
    int j = tid & 127, q = tid >> 7;
    const float* Lb = LfT + (b * EF) * FF + f0 + q * 2;
    const float* Rb = RfT + (b * EF) * FF;
    float s0 = 0.f, s1 = 0.f;
    for (int e = 0; e < EF; ++e) {
        float rj = Rb[e * FF + j];
        float2 lv = *(const float2*)&Lb[e * FF];
        float ae = fa[e];
        float v;
        v = lv.x + rj; v = fmaxf(v, 0.2f * v); s0 += v * ae;
        v = lv.y + rj; v = fmaxf(v, 0.2f * v); s1 += v * ae;
    }
    float ej[2] = {s0 + fbias[(f0 + q * 2) * FF + j],
                   s1 + fbias[(f0 + q * 2 + 1) * FF + j]};
    __shared__ float redA[4][2], redB[4][2];
    float m[2] = {ej[0], ej[1]};
#pragma unroll
    for (int off = 32; off > 0; off >>= 1) {
#pragma unroll
        for (int ii = 0; ii < 2; ++ii) m[ii] = fmaxf(m[ii], __shfl_xor(m[ii], off));
    }
    int wv = tid >> 6;
    if ((tid & 63) == 0) { redA[wv][0] = m[0]; redA[wv][1] = m[1]; }
    __syncthreads();
    float p[2], ps[2];
#pragma unroll
    for (int ii = 0; ii < 2; ++ii) {
        float mx = fmaxf(redA[wv][ii], redA[wv ^ 1][ii]);
        p[ii] = __expf(ej[ii] - mx);
        ps[ii] = p[ii];
    }
#pragma unroll
    for (int off = 32; off > 0; off >>= 1) {
#pragma unroll
        for (int ii = 0; ii < 2; ++ii) ps[ii] += __shfl_xor(ps[ii], off);
    }
    if ((tid & 63) == 0) { redB[wv][0] = ps[0]; redB[wv][1] = ps[1]; }
    __syncthreads();
    __shared__ float attQ[4][FF];
#pragma unroll
    for (int ii = 0; ii < 2; ++ii) {
        float inv = 1.f / (redB[wv][ii] + redB[wv ^ 1][ii]);
        attQ[q * 2 + ii][j] = p[ii] * inv;
    }
    __syncthreads();
    // PV + tanh + fcw-weighted reduce over w
    int w = tid & 127, ph = tid >> 7;
    float pv0 = 0.f, pv1 = 0.f;
    bool wok = (w < WW);
    float fcv = wok ? fcw[w] : 0.f;
    const float* a0 = attQ[ph * 2];
    const float* a1 = attQ[ph * 2 + 1];
    for (int jj = 0; jj < FF; ++jj) {
        float xv = wok ? x3T[(b * FF + jj) * WW + w] : 0.f;
        pv0 += a0[jj] * xv;
        pv1 += a1[jj] * xv;
    }
    float tv[2] = {tanhf(pv0) * fcv, tanhf(pv1) * fcv};
#pragma unroll
    for (int off = 32; off > 0; off >>= 1) {
#pragma unroll
        for (int ii = 0; ii < 2; ++ii) tv[ii] += __shfl_xor(tv[ii], off);
    }
    __shared__ float redT[4][2];
    if ((tid & 63) == 0) { redT[wv][0] = tv[0]; redT[wv][1] = tv[1]; }
    __syncthreads();
    if (tid < 4) {
        int hh = tid >> 1, ii = tid & 1;   // hh = ph, query = hh*2+ii
        tj[b * FF + f0 + hh * 2 + ii] = redT[hh * 2][ii] + redT[hh * 2 + 1][ii];
    }
}

// K6: out[b,f] = tanh(sum_j cos(f,j)*tj[b,j] + fcb). cos from normalized emb.
__global__ __launch_bounds__(128) void k_fc(const float* __restrict__ tjg,
                                            const float* __restrict__ emb,
                                            const float* __restrict__ fcb,
                                            float* __restrict__ out) {
    int b = blockIdx.x;
    int f = threadIdx.x;
    __shared__ float en[FF][12];
    __shared__ float tjs[FF];
    {
        float4 e0 = *(const float4*)&emb[f * 8];
        float4 e1 = *(const float4*)&emb[f * 8 + 4];
        float n = e0.x*e0.x + e0.y*e0.y + e0.z*e0.z + e0.w*e0.w +
                  e1.x*e1.x + e1.y*e1.y + e1.z*e1.z + e1.w*e1.w;
        float rin = rsqrtf(n);
        float4 a = make_float4(e0.x*rin, e0.y*rin, e0.z*rin, e0.w*rin);
        float4 c = make_float4(e1.x*rin, e1.y*rin, e1.z*rin, e1.w*rin);
        *(float4*)&en[f][0] = a;
        *(float4*)&en[f][4] = c;
        tjs[f] = tjg[b * FF + f];
    }
    __syncthreads();
    float er[8];
#pragma unroll
    for (int k = 0; k < 8; ++k) er[k] = en[f][k];
    float acc = fcb[0];
    for (int jj = 0; jj < FF; ++jj) {
        float4 a = *(const float4*)&en[jj][0];
        float4 c = *(const float4*)&en[jj][4];
        float d8 = er[0]*a.x + er[1]*a.y + er[2]*a.z + er[3]*a.w +
                   er[4]*c.x + er[5]*c.y + er[6]*c.z + er[7]*c.w;
        acc += d8 * tjs[jj];
    }
    out[b * FF + f] = tanhf(acc);
}

extern "C" void kernel_launch(void* const* d_in, const int* in_sizes, int n_in,
                              void* d_out, int out_size, void* d_ws, size_t ws_size,
                              hipStream_t stream) {
    const float* x     = (const float*)d_in[0];
    const float* cw    = (const float*)d_in[1];
    const float* cb    = (const float*)d_in[2];
    const float* tlw   = (const float*)d_in[3];
    const float* tlb   = (const float*)d_in[4];
    const float* ta    = (const float*)d_in[5];
    const float* tbias = (const float*)d_in[6];
    const float* flw   = (const float*)d_in[7];
    const float* flb   = (const float*)d_in[8];
    const float* fa    = (const float*)d_in[9];
    const float* fbias = (const float*)d_in[10];
    const float* emb   = (const float*)d_in[11];
    const float* fcw   = (const float*)d_in[12];
    const float* fcb   = (const float*)d_in[13];
    float* out = (float*)d_out;
    float* ws = (float*)d_ws;

    float* x2   = ws + 409600;
    float* x3T  = ws + 819200;
    float* LT   = ws + 1228800;   // reused as LfT
    float* Rt   = ws + 2048000;   // reused as RfT
    float* tj   = ws + 2867200;
    float* wt   = ws + 3297280;
    float* tlwT = ws + 3411968;
    float* flwT = ws + 3477504;

    k_prep<<<448, 256, 0, stream>>>(cw, tlw, flw, wt, tlwT, flwT);
    k_conv<<<BB * 10, 512, 0, stream>>>(x, wt, cb, x2);
    k_lr_t<<<BB * 13, 512, 0, stream>>>(x2, tlwT, tlb, LT, Rt);
    k_att_t<<<BB * 25, 256, 0, stream>>>(LT, Rt, ta, tbias, x2, x3T);
    k_lr_f<<<BB * 16, 512, 0, stream>>>(x3T, flwT, flb, LT, Rt);
    k_att_f<<<BB * 32, 256, 0, stream>>>(LT, Rt, fa, fbias, x3T, fcw, tj);
    k_fc<<<BB, 128, 0, stream>>>(tj, emb, fcb, out);
}

// Round 7
// 153.771 us; speedup vs baseline: 1.1230x; 1.1230x over previous
//
#include <hip/hip_runtime.h>
#include <math.h>

#define BB 32
#define WW 100
#define FF 128
#define KS 7
#define ET 256   // 2F (temporal GAT embed)
#define EF 200   // 2W (feature GAT embed)

// All multi-block-per-batch kernels use b = blockIdx & 31 (b-minor):
// BB=32 ≡ 0 (mod 8 XCDs) -> every tile of batch b lands on XCD b%8,
// so per-b panels (Rt/LT/x2/x3T) are HBM-fetched once and L2-served.

// ---------------- workspace layout (floats) ----------------
// x2:   409600   409600   conv output (B,W,F)
// x3T:  819200   409600   temporal GAT output, TRANSPOSED (B,F,W)
// LT:   1228800  819200   temporal left TRANSPOSED (B,256,100) -> reused LfT (B,200,128)
// Rt:   2048000  819200   temporal right TRANSPOSED (B,256,100) -> reused RfT (B,200,128)
// tj:   2867200  4096     tj[b][j] = sum_w fcw[w]*x4[b,w,j]
// wt:   3297280  114688   conv weights transposed (I,K,O)
// tlwT: 3411968  65536    temp_lin_w transposed (256,256)
// flwT: 3477504  40000    feat_lin_w transposed (200,200)

// K0: transpose the three weight tensors
__global__ void k_prep(const float* __restrict__ cw, const float* __restrict__ tlw,
                       const float* __restrict__ flw, float* __restrict__ wt,
                       float* __restrict__ tlwT, float* __restrict__ flwT) {
    int id = blockIdx.x * 256 + threadIdx.x;
    if (id < KS * FF * FF) {
        // wt[i][k][o] = cw[o][i][k]
        int o = id & (FF - 1);
        int r = id >> 7;
        int k = r % KS;
        int i = r / KS;
        wt[id] = cw[(o * FF + i) * KS + k];
    }
    if (id < ET * ET) {
        int e = id & (ET - 1);
        int d = id >> 8;
        tlwT[id] = tlw[e * ET + d];
    }
    if (id < EF * EF) {
        int e = id % EF;
        int d = id / EF;
        flwT[id] = flw[e * EF + d];
    }
}

// K1: Conv1d 'same' + relu, pos-encode fused into staging.
// 512 thr = (o:128) x (i-quarter h:4). TW=10, grid = 10 tiles x 32 b (b-minor).
#define CTW 10
#define NROW 16            // CTW + KS - 1
#define XPAD 20
__global__ __launch_bounds__(512) void k_conv(const float* __restrict__ x,
                                              const float* __restrict__ wt,
                                              const float* __restrict__ cb,
                                              float* __restrict__ x2) {
    int b = blockIdx.x & 31;
    int tile = blockIdx.x >> 5;
    int w0 = tile * CTW;
    int tid = threadIdx.x;
    int o = tid & (FF - 1);
    int h = tid >> 7;   // 0..3, i-quarter, wave-uniform
    __shared__ float xs[FF][XPAD];
    __shared__ float part[4][CTW][FF];
    for (int idx = tid; idx < NROW * FF; idx += 512) {
        int r = idx >> 7, f = idx & (FF - 1);
        int t = w0 - 3 + r;
        float v = 0.f;
        if ((unsigned)t < WW) {
            float div = __expf((float)f * (-9.210340371976184f / (float)FF));
            float arg = (float)t * div;
            v = x[(b * WW + t) * FF + f] + __sinf(arg) + __cosf(arg);
        }
        xs[f][r] = v;
    }
    __syncthreads();
    float acc[CTW];
#pragma unroll
    for (int t = 0; t < CTW; ++t) acc[t] = 0.f;
    const float* wbase = wt + (h * 32) * KS * FF + o;
#pragma unroll 2
    for (int il = 0; il < 32; ++il) {
        int i = h * 32 + il;
        float4 X0 = *(const float4*)&xs[i][0];
        float4 X1 = *(const float4*)&xs[i][4];
        float4 X2 = *(const float4*)&xs[i][8];
        float4 X3 = *(const float4*)&xs[i][12];
        float xr[16] = {X0.x, X0.y, X0.z, X0.w, X1.x, X1.y, X1.z, X1.w,
                        X2.x, X2.y, X2.z, X2.w, X3.x, X3.y, X3.z, X3.w};
        const float* wp = wbase + il * KS * FF;
#pragma unroll
        for (int k = 0; k < KS; ++k) {
            float wv = wp[k * FF];
#pragma unroll
            for (int t = 0; t < CTW; ++t) acc[t] += xr[t + k] * wv;
        }
    }
#pragma unroll
    for (int t = 0; t < CTW; ++t) part[h][t][o] = acc[t];
    __syncthreads();
    for (int idx = tid; idx < CTW * FF; idx += 512) {
        int t = idx >> 7, oo = idx & (FF - 1);
        float s = part[0][t][oo] + part[1][t][oo] + part[2][t][oo] +
                  part[3][t][oo] + cb[oo];
        x2[(b * WW + w0 + t) * FF + oo] = fmaxf(s, 0.f);
    }
}

// K2: temporal L/R GEMM. 512 thr = (e:256) x (row-half rh:2), 8 rows/block.
__global__ __launch_bounds__(512) void k_lr_t(const float* __restrict__ x2,
                                              const float* __restrict__ tlwT,
                                              const float* __restrict__ tlb,
                                              float* __restrict__ LT,
                                              float* __restrict__ Rt) {
    int b = blockIdx.x & 31;
    int tile = blockIdx.x >> 5;
    int i0 = tile * 8;
    int tid = threadIdx.x;
    int e = tid & 255;
    int rh = tid >> 8;
    __shared__ float xs[8][FF];
    for (int idx = tid; idx < 8 * FF; idx += 512) {
        int r = idx >> 7, d = idx & (FF - 1);
        int row = i0 + r; if (row >= WW) row = WW - 1;  // clamp (never stored)
        xs[r][d] = x2[(b * WW + row) * FF + d];
    }
    __syncthreads();
    float aL[4] = {0, 0, 0, 0}, aR[4] = {0, 0, 0, 0};
    const float* wl = tlwT + e;
#pragma unroll 2
    for (int dc = 0; dc < 32; ++dc) {
        float xv[4][4];
#pragma unroll
        for (int r = 0; r < 4; ++r)
            *(float4*)xv[r] = *(const float4*)&xs[rh * 4 + r][dc * 4];
#pragma unroll
        for (int q = 0; q < 4; ++q) {
            int d = dc * 4 + q;
            float wL = wl[d * ET];
            float wR = wl[(FF + d) * ET];
#pragma unroll
            for (int r = 0; r < 4; ++r) {
                aL[r] += xv[r][q] * wL;
                aR[r] += xv[r][q] * wR;
            }
        }
    }
    int ibase = i0 + rh * 4;
    if (ibase < WW) {
        float lb = tlb[e];
        float o0[4];
#pragma unroll
        for (int r = 0; r < 4; ++r) o0[r] = aL[r] + lb;
        *(float4*)&LT[(b * ET + e) * WW + ibase] = *(float4*)o0;
        *(float4*)&Rt[(b * ET + e) * WW + ibase] = *(float4*)aR;
    }
}

// K3: temporal attention, QT=4 queries/block (25 tiles x 32 b, b-minor).
__global__ __launch_bounds__(256) void k_att_t(const float* __restrict__ LT,
                                               const float* __restrict__ Rt,
                                               const float* __restrict__ ta,
                                               const float* __restrict__ tbias,
                                               const float* __restrict__ x2,
                                               float* __restrict__ x3T) {
    int b = blockIdx.x & 31;
    int tile = blockIdx.x >> 5;
    int i0 = tile * 4;
    int tid = threadIdx.x;
    int j = tid & 127, q = tid >> 7;
    const float* Lb = LT + (b * ET) * WW + i0 + q * 2;
    const float* Rb = Rt + (b * ET) * WW;
    float s0 = 0.f, s1 = 0.f;
#pragma unroll 4
    for (int e = 0; e < ET; ++e) {
        float rj = Rb[e * WW + j];
        float2 lv = *(const float2*)&Lb[e * WW];
        float ae = ta[e];
        float v;
        v = lv.x + rj; v = fmaxf(v, 0.2f * v); s0 += v * ae;
        v = lv.y + rj; v = fmaxf(v, 0.2f * v); s1 += v * ae;
    }
    float ej[2] = {s0, s1};
#pragma unroll
    for (int ii = 0; ii < 2; ++ii) {
        int i = i0 + q * 2 + ii;
        ej[ii] = (j < WW) ? ej[ii] + tbias[i * WW + j] : -1e30f;
    }
    __shared__ float redA[4][2], redB[4][2];
    float m[2] = {ej[0], ej[1]};
#pragma unroll
    for (int off = 32; off > 0; off >>= 1) {
#pragma unroll
        for (int ii = 0; ii < 2; ++ii) m[ii] = fmaxf(m[ii], __shfl_xor(m[ii], off));
    }
    int wv = tid >> 6;
    if ((tid & 63) == 0) { redA[wv][0] = m[0]; redA[wv][1] = m[1]; }
    __syncthreads();
    float p[2], ps[2];
#pragma unroll
    for (int ii = 0; ii < 2; ++ii) {
        float mx = fmaxf(redA[wv][ii], redA[wv ^ 1][ii]);
        p[ii] = (j < WW) ? __expf(ej[ii] - mx) : 0.f;
        ps[ii] = p[ii];
    }
#pragma unroll
    for (int off = 32; off > 0; off >>= 1) {
#pragma unroll
        for (int ii = 0; ii < 2; ++ii) ps[ii] += __shfl_xor(ps[ii], off);
    }
    if ((tid & 63) == 0) { redB[wv][0] = ps[0]; redB[wv][1] = ps[1]; }
    __syncthreads();
    __shared__ float attQ[4][WW];
    if (j < WW) {
#pragma unroll
        for (int ii = 0; ii < 2; ++ii) {
            float inv = 1.f / (redB[wv][ii] + redB[wv ^ 1][ii]);
            attQ[q * 2 + ii][j] = p[ii] * inv;
        }
    }
    __syncthreads();
    int d = tid & 127, ph = tid >> 7;
    float pv0 = 0.f, pv1 = 0.f;
    const float* a0 = attQ[ph * 2];
    const float* a1 = attQ[ph * 2 + 1];
#pragma unroll 4
    for (int jj = 0; jj < WW; ++jj) {
        float xv = x2[(b * WW + jj) * FF + d];
        pv0 += a0[jj] * xv;
        pv1 += a1[jj] * xv;
    }
    __shared__ float ob[4][FF];
    ob[ph * 2][d] = tanhf(pv0);
    ob[ph * 2 + 1][d] = tanhf(pv1);
    __syncthreads();
    if (tid < FF) {
        float4 v = make_float4(ob[0][tid], ob[1][tid], ob[2][tid], ob[3][tid]);
        *(float4*)&x3T[(b * FF + tid) * WW + i0] = v;
    }
}

// K4: feature L/R GEMM. 512 thr = (e:256, valid<200) x (rh:2), 8 f-rows/block.
__global__ __launch_bounds__(512) void k_lr_f(const float* __restrict__ x3T,
                                              const float* __restrict__ flwT,
                                              const float* __restrict__ flb,
                                              float* __restrict__ LfT,
                                              float* __restrict__ RfT) {
    int b = blockIdx.x & 31;
    int tile = blockIdx.x >> 5;
    int f0 = tile * 8;
    int tid = threadIdx.x;
    int e = tid & 255;
    int rh = tid >> 8;
    __shared__ float xs[8][WW];
    for (int idx = tid; idx < 8 * WW; idx += 512) {
        int r = idx / WW, d = idx % WW;
        xs[r][d] = x3T[(b * FF + f0 + r) * WW + d];
    }
    __syncthreads();
    if (e < EF) {
        float aL[4] = {0, 0, 0, 0}, aR[4] = {0, 0, 0, 0};
        const float* wl = flwT + e;
#pragma unroll 2
        for (int dc = 0; dc < 25; ++dc) {
            float xv[4][4];
#pragma unroll
            for (int r = 0; r < 4; ++r)
                *(float4*)xv[r] = *(const float4*)&xs[rh * 4 + r][dc * 4];
#pragma unroll
            for (int q = 0; q < 4; ++q) {
                int d = dc * 4 + q;
                float wL = wl[d * EF];
                float wR = wl[(WW + d) * EF];
#pragma unroll
                for (int r = 0; r < 4; ++r) {
                    aL[r] += xv[r][q] * wL;
                    aR[r] += xv[r][q] * wR;
                }
            }
        }
        float lb = flb[e];
        float o0[4];
#pragma unroll
        for (int r = 0; r < 4; ++r) o0[r] = aL[r] + lb;
        int fbase = f0 + rh * 4;
        *(float4*)&LfT[(b * EF + e) * FF + fbase] = *(float4*)o0;
        *(float4*)&RfT[(b * EF + e) * FF + fbase] = *(float4*)aR;
    }
}

// K5: feature attention, QT=4 (32 tiles x 32 b, b-minor) + fused tj reduction.
__global__ __launch_bounds__(256) void k_att_f(const float* __restrict__ LfT,
                                               const float* __restrict__ RfT,
                                               const float* __restrict__ fa,
                                               const float* __restrict__ fbias,
                                               const float* __restrict__ x3T,
                                               const float* __restrict__ fcw,
                                               float* __restrict__ tj) {
    int b = blockIdx.x & 31;
    int tile = blockIdx.x >> 5;
    int f0 = tile * 4;
    int tid = threadIdx.x;
    int j = tid & 127, q = tid >> 7;
    const float* Lb = LfT + (b * EF) * FF + f0 + q * 2;
    const float* Rb = RfT + (b * EF) * FF;
    float s0 = 0.f, s1 = 0.f;
#pragma unroll 4
    for (int e = 0; e < EF; ++e) {
        float rj = Rb[e * FF + j];
        float2 lv = *(const float2*)&Lb[e * FF];
        float ae = fa[e];
        float v;
        v = lv.x + rj; v = fmaxf(v, 0.2f * v); s0 += v * ae;
        v = lv.y + rj; v = fmaxf(v, 0.2f * v); s1 += v * ae;
    }
    float ej[2] = {s0 + fbias[(f0 + q * 2) * FF + j],
                   s1 + fbias[(f0 + q * 2 + 1) * FF + j]};
    __shared__ float redA[4][2], redB[4][2];
    float m[2] = {ej[0], ej[1]};
#pragma unroll
    for (int off = 32; off > 0; off >>= 1) {
#pragma unroll
        for (int ii = 0; ii < 2; ++ii) m[ii] = fmaxf(m[ii], __shfl_xor(m[ii], off));
    }
    int wv = tid >> 6;
    if ((tid & 63) == 0) { redA[wv][0] = m[0]; redA[wv][1] = m[1]; }
    __syncthreads();
    float p[2], ps[2];
#pragma unroll
    for (int ii = 0; ii < 2; ++ii) {
        float mx = fmaxf(redA[wv][ii], redA[wv ^ 1][ii]);
        p[ii] = __expf(ej[ii] - mx);
        ps[ii] = p[ii];
    }
#pragma unroll
    for (int off = 32; off > 0; off >>= 1) {
#pragma unroll
        for (int ii = 0; ii < 2; ++ii) ps[ii] += __shfl_xor(ps[ii], off);
    }
    if ((tid & 63) == 0) { redB[wv][0] = ps[0]; redB[wv][1] = ps[1]; }
    __syncthreads();
    __shared__ float attQ[4][FF];
#pragma unroll
    for (int ii = 0; ii < 2; ++ii) {
        float inv = 1.f / (redB[wv][ii] + redB[wv ^ 1][ii]);
        attQ[q * 2 + ii][j] = p[ii] * inv;
    }
    __syncthreads();
    int w = tid & 127, ph = tid >> 7;
    float pv0 = 0.f, pv1 = 0.f;
    bool wok = (w < WW);
    float fcv = wok ? fcw[w] : 0.f;
    const float* a0 = attQ[ph * 2];
    const float* a1 = attQ[ph * 2 + 1];
#pragma unroll 4
    for (int jj = 0; jj < FF; ++jj) {
        float xv = wok ? x3T[(b * FF + jj) * WW + w] : 0.f;
        pv0 += a0[jj] * xv;
        pv1 += a1[jj] * xv;
    }
    float tv[2] = {tanhf(pv0) * fcv, tanhf(pv1) * fcv};
#pragma unroll
    for (int off = 32; off > 0; off >>= 1) {
#pragma unroll
        for (int ii = 0; ii < 2; ++ii) tv[ii] += __shfl_xor(tv[ii], off);
    }
    __shared__ float redT[4][2];
    if ((tid & 63) == 0) { redT[wv][0] = tv[0]; redT[wv][1] = tv[1]; }
    __syncthreads();
    if (tid < 4) {
        int hh = tid >> 1, ii = tid & 1;
        tj[b * FF + f0 + hh * 2 + ii] = redT[hh * 2][ii] + redT[hh * 2 + 1][ii];
    }
}

// K6: out[b,f] = tanh(sum_j cos(f,j)*tj[b,j] + fcb). cos from normalized emb.
__global__ __launch_bounds__(128) void k_fc(const float* __restrict__ tjg,
                                            const float* __restrict__ emb,
                                            const float* __restrict__ fcb,
                                            float* __restrict__ out) {
    int b = blockIdx.x;
    int f = threadIdx.x;
    __shared__ float en[FF][12];
    __shared__ float tjs[FF];
    {
        float4 e0 = *(const float4*)&emb[f * 8];
        float4 e1 = *(const float4*)&emb[f * 8 + 4];
        float n = e0.x*e0.x + e0.y*e0.y + e0.z*e0.z + e0.w*e0.w +
                  e1.x*e1.x + e1.y*e1.y + e1.z*e1.z + e1.w*e1.w;
        float rin = rsqrtf(n);
        float4 a = make_float4(e0.x*rin, e0.y*rin, e0.z*rin, e0.w*rin);
        float4 c = make_float4(e1.x*rin, e1.y*rin, e1.z*rin, e1.w*rin);
        *(float4*)&en[f][0] = a;
        *(float4*)&en[f][4] = c;
        tjs[f] = tjg[b * FF + f];
    }
    __syncthreads();
    float er[8];
#pragma unroll
    for (int k = 0; k < 8; ++k) er[k] = en[f][k];
    float acc = fcb[0];
    for (int jj = 0; jj < FF; ++jj) {
        float4 a = *(const float4*)&en[jj][0];
        float4 c = *(const float4*)&en[jj][4];
        float d8 = er[0]*a.x + er[1]*a.y + er[2]*a.z + er[3]*a.w +
                   er[4]*c.x + er[5]*c.y + er[6]*c.z + er[7]*c.w;
        acc += d8 * tjs[jj];
    }
    out[b * FF + f] = tanhf(acc);
}

extern "C" void kernel_launch(void* const* d_in, const int* in_sizes, int n_in,
                              void* d_out, int out_size, void* d_ws, size_t ws_size,
                              hipStream_t stream) {
    const float* x     = (const float*)d_in[0];
    const float* cw    = (const float*)d_in[1];
    const float* cb    = (const float*)d_in[2];
    const float* tlw   = (const float*)d_in[3];
    const float* tlb   = (const float*)d_in[4];
    const float* ta    = (const float*)d_in[5];
    const float* tbias = (const float*)d_in[6];
    const float* flw   = (const float*)d_in[7];
    const float* flb   = (const float*)d_in[8];
    const float* fa    = (const float*)d_in[9];
    const float* fbias = (const float*)d_in[10];
    const float* emb   = (const float*)d_in[11];
    const float* fcw   = (const float*)d_in[12];
    const float* fcb   = (const float*)d_in[13];
    float* out = (float*)d_out;
    float* ws = (float*)d_ws;

    float* x2   = ws + 409600;
    float* x3T  = ws + 819200;
    float* LT   = ws + 1228800;   // reused as LfT
    float* Rt   = ws + 2048000;   // reused as RfT
    float* tj   = ws + 2867200;
    float* wt   = ws + 3297280;
    float* tlwT = ws + 3411968;
    float* flwT = ws + 3477504;

    k_prep<<<448, 256, 0, stream>>>(cw, tlw, flw, wt, tlwT, flwT);
    k_conv<<<BB * 10, 512, 0, stream>>>(x, wt, cb, x2);
    k_lr_t<<<BB * 13, 512, 0, stream>>>(x2, tlwT, tlb, LT, Rt);
    k_att_t<<<BB * 25, 256, 0, stream>>>(LT, Rt, ta, tbias, x2, x3T);
    k_lr_f<<<BB * 16, 512, 0, stream>>>(x3T, flwT, flb, LT, Rt);
    k_att_f<<<BB * 32, 256, 0, stream>>>(LT, Rt, fa, fbias, x3T, fcw, tj);
    k_fc<<<BB, 128, 0, stream>>>(tj, emb, fcb, out);
}

// Round 8
// 149.533 us; speedup vs baseline: 1.1548x; 1.0283x over previous
//
#include <hip/hip_runtime.h>
#include <math.h>

#define BB 32
#define WW 100
#define FF 128
#define KS 7
#define ET 256   // 2F (temporal GAT embed)
#define EF 200   // 2W (feature GAT embed)

// b = blockIdx & 31 (b-minor): BB=32 ≡ 0 mod 8 XCDs -> all tiles of batch b
// land on one XCD; per-b panels are HBM-fetched once, then L2-served.

// ---------------- workspace layout (floats) ----------------
// x2:   409600   409600   conv output (B,W,F)
// x3T:  819200   409600   temporal GAT output, TRANSPOSED (B,F,W)
// LT:   1228800  819200   temporal left TRANSPOSED (B,256,100) -> reused LfT (B,200,128)
// Rt:   2048000  819200   temporal right TRANSPOSED (B,256,100) -> reused RfT (B,200,128)
// tj:   2867200  4096
// wt:   3297280  114688   conv weights (I,K,O)
// tlwT: 3411968  65536    temp_lin_w transposed
// flwT: 3477504  40000    feat_lin_w transposed

__global__ void k_prep(const float* __restrict__ cw, const float* __restrict__ tlw,
                       const float* __restrict__ flw, float* __restrict__ wt,
                       float* __restrict__ tlwT, float* __restrict__ flwT) {
    int id = blockIdx.x * 256 + threadIdx.x;
    if (id < KS * FF * FF) {
        int o = id & (FF - 1);
        int r = id >> 7;
        int k = r % KS;
        int i = r / KS;
        wt[id] = cw[(o * FF + i) * KS + k];
    }
    if (id < ET * ET) {
        int e = id & (ET - 1);
        int d = id >> 8;
        tlwT[id] = tlw[e * ET + d];
    }
    if (id < EF * EF) {
        int e = id % EF;
        int d = id / EF;
        flwT[id] = flw[e * EF + d];
    }
}

// K1: Conv1d 'same' + relu, pos-encode fused into staging. (unchanged)
#define CTW 10
#define NROW 16
#define XPAD 20
__global__ __launch_bounds__(512) void k_conv(const float* __restrict__ x,
                                              const float* __restrict__ wt,
                                              const float* __restrict__ cb,
                                              float* __restrict__ x2) {
    int b = blockIdx.x & 31;
    int tile = blockIdx.x >> 5;
    int w0 = tile * CTW;
    int tid = threadIdx.x;
    int o = tid & (FF - 1);
    int h = tid >> 7;
    __shared__ float xs[FF][XPAD];
    __shared__ float part[4][CTW][FF];
    for (int idx = tid; idx < NROW * FF; idx += 512) {
        int r = idx >> 7, f = idx & (FF - 1);
        int t = w0 - 3 + r;
        float v = 0.f;
        if ((unsigned)t < WW) {
            float div = __expf((float)f * (-9.210340371976184f / (float)FF));
            float arg = (float)t * div;
            v = x[(b * WW + t) * FF + f] + __sinf(arg) + __cosf(arg);
        }
        xs[f][r] = v;
    }
    __syncthreads();
    float acc[CTW];
#pragma unroll
    for (int t = 0; t < CTW; ++t) acc[t] = 0.f;
    const float* wbase = wt + (h * 32) * KS * FF + o;
#pragma unroll 2
    for (int il = 0; il < 32; ++il) {
        int i = h * 32 + il;
        float4 X0 = *(const float4*)&xs[i][0];
        float4 X1 = *(const float4*)&xs[i][4];
        float4 X2 = *(const float4*)&xs[i][8];
        float4 X3 = *(const float4*)&xs[i][12];
        float xr[16] = {X0.x, X0.y, X0.z, X0.w, X1.x, X1.y, X1.z, X1.w,
                        X2.x, X2.y, X2.z, X2.w, X3.x, X3.y, X3.z, X3.w};
        const float* wp = wbase + il * KS * FF;
#pragma unroll
        for (int k = 0; k < KS; ++k) {
            float wv = wp[k * FF];
#pragma unroll
            for (int t = 0; t < CTW; ++t) acc[t] += xr[t + k] * wv;
        }
    }
#pragma unroll
    for (int t = 0; t < CTW; ++t) part[h][t][o] = acc[t];
    __syncthreads();
    for (int idx = tid; idx < CTW * FF; idx += 512) {
        int t = idx >> 7, oo = idx & (FF - 1);
        float s = part[0][t][oo] + part[1][t][oo] + part[2][t][oo] +
                  part[3][t][oo] + cb[oo];
        x2[(b * WW + w0 + t) * FF + oo] = fmaxf(s, 0.f);
    }
}

// K2: temporal L/R GEMM. (unchanged)
__global__ __launch_bounds__(512) void k_lr_t(const float* __restrict__ x2,
                                              const float* __restrict__ tlwT,
                                              const float* __restrict__ tlb,
                                              float* __restrict__ LT,
                                              float* __restrict__ Rt) {
    int b = blockIdx.x & 31;
    int tile = blockIdx.x >> 5;
    int i0 = tile * 8;
    int tid = threadIdx.x;
    int e = tid & 255;
    int rh = tid >> 8;
    __shared__ float xs[8][FF];
    for (int idx = tid; idx < 8 * FF; idx += 512) {
        int r = idx >> 7, d = idx & (FF - 1);
        int row = i0 + r; if (row >= WW) row = WW - 1;
        xs[r][d] = x2[(b * WW + row) * FF + d];
    }
    __syncthreads();
    float aL[4] = {0, 0, 0, 0}, aR[4] = {0, 0, 0, 0};
    const float* wl = tlwT + e;
#pragma unroll 2
    for (int dc = 0; dc < 32; ++dc) {
        float xv[4][4];
#pragma unroll
        for (int r = 0; r < 4; ++r)
            *(float4*)xv[r] = *(const float4*)&xs[rh * 4 + r][dc * 4];
#pragma unroll
        for (int q = 0; q < 4; ++q) {
            int d = dc * 4 + q;
            float wL = wl[d * ET];
            float wR = wl[(FF + d) * ET];
#pragma unroll
            for (int r = 0; r < 4; ++r) {
                aL[r] += xv[r][q] * wL;
                aR[r] += xv[r][q] * wR;
            }
        }
    }
    int ibase = i0 + rh * 4;
    if (ibase < WW) {
        float lb = tlb[e];
        float o0[4];
#pragma unroll
        for (int r = 0; r < 4; ++r) o0[r] = aL[r] + lb;
        *(float4*)&LT[(b * ET + e) * WW + ibase] = *(float4*)o0;
        *(float4*)&Rt[(b * ET + e) * WW + ibase] = *(float4*)aR;
    }
}

// K3: temporal attention, QT=8, chunked-LDS score + PV (all inner loops LDS/VALU).
__global__ __launch_bounds__(256) void k_att_t(const float* __restrict__ LT,
                                               const float* __restrict__ Rt,
                                               const float* __restrict__ ta,
                                               const float* __restrict__ tbias,
                                               const float* __restrict__ x2,
                                               float* __restrict__ x3T) {
    int b = blockIdx.x & 31;
    int tile = blockIdx.x >> 5;   // 0..12
    int i0 = tile * 8;
    int tid = threadIdx.x;
    int j = tid & 127, q = tid >> 7;
    __shared__ float Rs[32][FF];      // reused: R-chunk, then x2-chunk
    __shared__ float Ls[32][8];
    __shared__ float attQT[FF][8];
    __shared__ float ob[8][FF];
    __shared__ float redA[4][4], redB[4][4];
    float s[4] = {0.f, 0.f, 0.f, 0.f};
    for (int ch = 0; ch < 8; ++ch) {
        int e0 = ch * 32;
        for (int idx = tid; idx < 32 * FF; idx += 256) {
            int er = idx >> 7, w = idx & 127;
            Rs[er][w] = (w < WW) ? Rt[(b * ET + e0 + er) * WW + w] : 0.f;
        }
        {
            int er = tid >> 3, qq = tid & 7;
            Ls[er][qq] = LT[(b * ET + e0 + er) * WW + i0 + qq];
        }
        __syncthreads();
#pragma unroll 4
        for (int e = 0; e < 32; ++e) {
            float rj = Rs[e][j];
            float ae = ta[e0 + e];
            float4 lv = *(const float4*)&Ls[e][q * 4];
            float v;
            v = lv.x + rj; v = fmaxf(v, 0.2f * v); s[0] += v * ae;
            v = lv.y + rj; v = fmaxf(v, 0.2f * v); s[1] += v * ae;
            v = lv.z + rj; v = fmaxf(v, 0.2f * v); s[2] += v * ae;
            v = lv.w + rj; v = fmaxf(v, 0.2f * v); s[3] += v * ae;
        }
        __syncthreads();
    }
    float ej[4];
#pragma unroll
    for (int ii = 0; ii < 4; ++ii) {
        int i = i0 + q * 4 + ii;
        float bv = (j < WW && i < WW) ? tbias[i * WW + j] : 0.f;
        ej[ii] = (j < WW) ? s[ii] + bv : -1e30f;
    }
    float m[4] = {ej[0], ej[1], ej[2], ej[3]};
#pragma unroll
    for (int off = 32; off > 0; off >>= 1) {
#pragma unroll
        for (int ii = 0; ii < 4; ++ii) m[ii] = fmaxf(m[ii], __shfl_xor(m[ii], off));
    }
    int wv = tid >> 6;
    if ((tid & 63) == 0) {
#pragma unroll
        for (int ii = 0; ii < 4; ++ii) redA[wv][ii] = m[ii];
    }
    __syncthreads();
    float p[4], ps[4];
#pragma unroll
    for (int ii = 0; ii < 4; ++ii) {
        float mx = fmaxf(redA[wv][ii], redA[wv ^ 1][ii]);
        p[ii] = (j < WW) ? __expf(ej[ii] - mx) : 0.f;
        ps[ii] = p[ii];
    }
#pragma unroll
    for (int off = 32; off > 0; off >>= 1) {
#pragma unroll
        for (int ii = 0; ii < 4; ++ii) ps[ii] += __shfl_xor(ps[ii], off);
    }
    if ((tid & 63) == 0) {
#pragma unroll
        for (int ii = 0; ii < 4; ++ii) redB[wv][ii] = ps[ii];
    }
    __syncthreads();
#pragma unroll
    for (int ii = 0; ii < 4; ++ii) {
        float inv = 1.f / (redB[wv][ii] + redB[wv ^ 1][ii]);
        attQT[j][q * 4 + ii] = p[ii] * inv;
    }
    // PV: threads = d(128) x ph(2); x2 rows staged via Rs in 4 chunks of 25
    int d = tid & 127, ph = tid >> 7;
    float pv[4] = {0.f, 0.f, 0.f, 0.f};
    for (int jc = 0; jc < 4; ++jc) {
        __syncthreads();
        for (int idx = tid; idx < 25 * FF; idx += 256) {
            int r = idx >> 7, f = idx & 127;
            Rs[r][f] = x2[(b * WW + jc * 25 + r) * FF + f];
        }
        __syncthreads();
#pragma unroll 5
        for (int r = 0; r < 25; ++r) {
            float xv = Rs[r][d];
            float4 av = *(const float4*)&attQT[jc * 25 + r][ph * 4];
            pv[0] += av.x * xv; pv[1] += av.y * xv;
            pv[2] += av.z * xv; pv[3] += av.w * xv;
        }
    }
#pragma unroll
    for (int ii = 0; ii < 4; ++ii) ob[ph * 4 + ii][d] = tanhf(pv[ii]);
    __syncthreads();
    if (tid < FF) {
        int f = tid;
        float4 v0 = make_float4(ob[0][f], ob[1][f], ob[2][f], ob[3][f]);
        *(float4*)&x3T[(b * FF + f) * WW + i0] = v0;
        if (i0 + 4 < WW) {
            float4 v1 = make_float4(ob[4][f], ob[5][f], ob[6][f], ob[7][f]);
            *(float4*)&x3T[(b * FF + f) * WW + i0 + 4] = v1;
        }
    }
}

// K4: feature L/R GEMM. (unchanged)
__global__ __launch_bounds__(512) void k_lr_f(const float* __restrict__ x3T,
                                              const float* __restrict__ flwT,
                                              const float* __restrict__ flb,
                                              float* __restrict__ LfT,
                                              float* __restrict__ RfT) {
    int b = blockIdx.x & 31;
    int tile = blockIdx.x >> 5;
    int f0 = tile * 8;
    int tid = threadIdx.x;
    int e = tid & 255;
    int rh = tid >> 8;
    __shared__ float xs[8][WW];
    for (int idx = tid; idx < 8 * WW; idx += 512) {
        int r = idx / WW, d = idx % WW;
        xs[r][d] = x3T[(b * FF + f0 + r) * WW + d];
    }
    __syncthreads();
    if (e < EF) {
        float aL[4] = {0, 0, 0, 0}, aR[4] = {0, 0, 0, 0};
        const float* wl = flwT + e;
#pragma unroll 2
        for (int dc = 0; dc < 25; ++dc) {
            float xv[4][4];
#pragma unroll
            for (int r = 0; r < 4; ++r)
                *(float4*)xv[r] = *(const float4*)&xs[rh * 4 + r][dc * 4];
#pragma unroll
            for (int q = 0; q < 4; ++q) {
                int d = dc * 4 + q;
                float wL = wl[d * EF];
                float wR = wl[(WW + d) * EF];
#pragma unroll
                for (int r = 0; r < 4; ++r) {
                    aL[r] += xv[r][q] * wL;
                    aR[r] += xv[r][q] * wR;
                }
            }
        }
        float lb = flb[e];
        float o0[4];
#pragma unroll
        for (int r = 0; r < 4; ++r) o0[r] = aL[r] + lb;
        int fbase = f0 + rh * 4;
        *(float4*)&LfT[(b * EF + e) * FF + fbase] = *(float4*)o0;
        *(float4*)&RfT[(b * EF + e) * FF + fbase] = *(float4*)aR;
    }
}

// K5: feature attention, QT=8, chunked-LDS score + PV, fused tj reduction.
__global__ __launch_bounds__(256) void k_att_f(const float* __restrict__ LfT,
                                               const float* __restrict__ RfT,
                                               const float* __restrict__ fa,
                                               const float* __restrict__ fbias,
                                               const float* __restrict__ x3T,
                                               const float* __restrict__ fcw,
                                               float* __restrict__ tj) {
    int b = blockIdx.x & 31;
    int tile = blockIdx.x >> 5;   // 0..15
    int f0 = tile * 8;
    int tid = threadIdx.x;
    int j = tid & 127, q = tid >> 7;
    __shared__ float Rs[32][FF];
    __shared__ float Ls[32][8];
    __shared__ float attQT[FF][8];
    __shared__ float redA[4][4], redB[4][4], redT[4][4];
    float s[4] = {0.f, 0.f, 0.f, 0.f};
    for (int ch = 0; ch < 8; ++ch) {
        int e0 = ch * 25;
        for (int idx = tid; idx < 25 * FF; idx += 256) {
            int er = idx >> 7, f = idx & 127;
            Rs[er][f] = RfT[(b * EF + e0 + er) * FF + f];
        }
        if (tid < 200) {
            int er = tid >> 3, qq = tid & 7;
            Ls[er][qq] = LfT[(b * EF + e0 + er) * FF + f0 + qq];
        }
        __syncthreads();
#pragma unroll 5
        for (int e = 0; e < 25; ++e) {
            float rj = Rs[e][j];
            float ae = fa[e0 + e];
            float4 lv = *(const float4*)&Ls[e][q * 4];
            float v;
            v = lv.x + rj; v = fmaxf(v, 0.2f * v); s[0] += v * ae;
            v = lv.y + rj; v = fmaxf(v, 0.2f * v); s[1] += v * ae;
            v = lv.z + rj; v = fmaxf(v, 0.2f * v); s[2] += v * ae;
            v = lv.w + rj; v = fmaxf(v, 0.2f * v); s[3] += v * ae;
        }
        __syncthreads();
    }
    float ej[4];
#pragma unroll
    for (int ii = 0; ii < 4; ++ii)
        ej[ii] = s[ii] + fbias[(f0 + q * 4 + ii) * FF + j];
    float m[4] = {ej[0], ej[1], ej[2], ej[3]};
#pragma unroll
    for (int off = 32; off > 0; off >>= 1) {
#pragma unroll
        for (int ii = 0; ii < 4; ++ii) m[ii] = fmaxf(m[ii], __shfl_xor(m[ii], off));
    }
    int wv = tid >> 6;
    if ((tid & 63) == 0) {
#pragma unroll
        for (int ii = 0; ii < 4; ++ii) redA[wv][ii] = m[ii];
    }
    __syncthreads();
    float p[4], ps[4];
#pragma unroll
    for (int ii = 0; ii < 4; ++ii) {
        float mx = fmaxf(redA[wv][ii], redA[wv ^ 1][ii]);
        p[ii] = __expf(ej[ii] - mx);
        ps[ii] = p[ii];
    }
#pragma unroll
    for (int off = 32; off > 0; off >>= 1) {
#pragma unroll
        for (int ii = 0; ii < 4; ++ii) ps[ii] += __shfl_xor(ps[ii], off);
    }
    if ((tid & 63) == 0) {
#pragma unroll
        for (int ii = 0; ii < 4; ++ii) redB[wv][ii] = ps[ii];
    }
    __syncthreads();
#pragma unroll
    for (int ii = 0; ii < 4; ++ii) {
        float inv = 1.f / (redB[wv][ii] + redB[wv ^ 1][ii]);
        attQT[j][q * 4 + ii] = p[ii] * inv;
    }
    // PV: threads = w(128) x ph(2); x3T rows staged via Rs in 4 chunks of 32
    int w = tid & 127, ph = tid >> 7;
    float pv[4] = {0.f, 0.f, 0.f, 0.f};
    for (int jc = 0; jc < 4; ++jc) {
        __syncthreads();
        for (int idx = tid; idx < 32 * FF; idx += 256) {
            int r = idx >> 7, ww = idx & 127;
            Rs[r][ww] = (ww < WW) ? x3T[(b * FF + jc * 32 + r) * WW + ww] : 0.f;
        }
        __syncthreads();
#pragma unroll 4
        for (int r = 0; r < 32; ++r) {
            float xv = Rs[r][w];
            float4 av = *(const float4*)&attQT[jc * 32 + r][ph * 4];
            pv[0] += av.x * xv; pv[1] += av.y * xv;
            pv[2] += av.z * xv; pv[3] += av.w * xv;
        }
    }
    bool wok = (w < WW);
    float fcv = wok ? fcw[w] : 0.f;
    float tv[4];
#pragma unroll
    for (int ii = 0; ii < 4; ++ii) tv[ii] = tanhf(pv[ii]) * fcv;
#pragma unroll
    for (int off = 32; off > 0; off >>= 1) {
#pragma unroll
        for (int ii = 0; ii < 4; ++ii) tv[ii] += __shfl_xor(tv[ii], off);
    }
    if ((tid & 63) == 0) {
#pragma unroll
        for (int ii = 0; ii < 4; ++ii) redT[wv][ii] = tv[ii];
    }
    __syncthreads();
    if (tid < 8) {
        int hh = tid >> 2, ii = tid & 3;   // hh = ph
        tj[b * FF + f0 + hh * 4 + ii] = redT[hh * 2][ii] + redT[hh * 2 + 1][ii];
    }
}

// K6: out[b,f] = tanh(sum_j cos(f,j)*tj[b,j] + fcb). (unchanged)
__global__ __launch_bounds__(128) void k_fc(const float* __restrict__ tjg,
                                            const float* __restrict__ emb,
                                            const float* __restrict__ fcb,
                                            float* __restrict__ out) {
    int b = blockIdx.x;
    int f = threadIdx.x;
    __shared__ float en[FF][12];
    __shared__ float tjs[FF];
    {
        float4 e0 = *(const float4*)&emb[f * 8];
        float4 e1 = *(const float4*)&emb[f * 8 + 4];
        float n = e0.x*e0.x + e0.y*e0.y + e0.z*e0.z + e0.w*e0.w +
                  e1.x*e1.x + e1.y*e1.y + e1.z*e1.z + e1.w*e1.w;
        float rin = rsqrtf(n);
        float4 a = make_float4(e0.x*rin, e0.y*rin, e0.z*rin, e0.w*rin);
        float4 c = make_float4(e1.x*rin, e1.y*rin, e1.z*rin, e1.w*rin);
        *(float4*)&en[f][0] = a;
        *(float4*)&en[f][4] = c;
        tjs[f] = tjg[b * FF + f];
    }
    __syncthreads();
    float er[8];
#pragma unroll
    for (int k = 0; k < 8; ++k) er[k] = en[f][k];
    float acc = fcb[0];
    for (int jj = 0; jj < FF; ++jj) {
        float4 a = *(const float4*)&en[jj][0];
        float4 c = *(const float4*)&en[jj][4];
        float d8 = er[0]*a.x + er[1]*a.y + er[2]*a.z + er[3]*a.w +
                   er[4]*c.x + er[5]*c.y + er[6]*c.z + er[7]*c.w;
        acc += d8 * tjs[jj];
    }
    out[b * FF + f] = tanhf(acc);
}

extern "C" void kernel_launch(void* const* d_in, const int* in_sizes, int n_in,
                              void* d_out, int out_size, void* d_ws, size_t ws_size,
                              hipStream_t stream) {
    const float* x     = (const float*)d_in[0];
    const float* cw    = (const float*)d_in[1];
    const float* cb    = (const float*)d_in[2];
    const float* tlw   = (const float*)d_in[3];
    const float* tlb   = (const float*)d_in[4];
    const float* ta    = (const float*)d_in[5];
    const float* tbias = (const float*)d_in[6];
    const float* flw   = (const float*)d_in[7];
    const float* flb   = (const float*)d_in[8];
    const float* fa    = (const float*)d_in[9];
    const float* fbias = (const float*)d_in[10];
    const float* emb   = (const float*)d_in[11];
    const float* fcw   = (const float*)d_in[12];
    const float* fcb   = (const float*)d_in[13];
    float* out = (float*)d_out;
    float* ws = (float*)d_ws;

    float* x2   = ws + 409600;
    float* x3T  = ws + 819200;
    float* LT   = ws + 1228800;   // reused as LfT
    float* Rt   = ws + 2048000;   // reused as RfT
    float* tj   = ws + 2867200;
    float* wt   = ws + 3297280;
    float* tlwT = ws + 3411968;
    float* flwT = ws + 3477504;

    k_prep<<<448, 256, 0, stream>>>(cw, tlw, flw, wt, tlwT, flwT);
    k_conv<<<BB * 10, 512, 0, stream>>>(x, wt, cb, x2);
    k_lr_t<<<BB * 13, 512, 0, stream>>>(x2, tlwT, tlb, LT, Rt);
    k_att_t<<<BB * 13, 256, 0, stream>>>(LT, Rt, ta, tbias, x2, x3T);
    k_lr_f<<<BB * 16, 512, 0, stream>>>(x3T, flwT, flb, LT, Rt);
    k_att_f<<<BB * 16, 256, 0, stream>>>(LT, Rt, fa, fbias, x3T, fcw, tj);
    k_fc<<<BB, 128, 0, stream>>>(tj, emb, fcb, out);
}

// Round 9
// 141.132 us; speedup vs baseline: 1.2235x; 1.0595x over previous
//
#include <hip/hip_runtime.h>
#include <math.h>

#define BB 32
#define WW 100
#define FF 128
#define KS 7
#define ET 256   // 2F (temporal GAT embed)
#define EF 200   // 2W (feature GAT embed)

// b = blockIdx & 31 (b-minor): BB=32 ≡ 0 mod 8 XCDs -> all tiles of batch b
// land on one XCD; per-b panels are HBM-fetched once, then L2-served.

// ---------------- workspace layout (floats) ----------------
// x2:   409600   409600   conv output (B,W,F)
// x3T:  819200   409600   temporal GAT output, TRANSPOSED (B,F,W)
// LT:   1228800  819200   temporal left TRANSPOSED (B,256,100) -> reused LfT (B,200,128)
// Rt:   2048000  819200   temporal right TRANSPOSED (B,256,100) -> reused RfT (B,200,128)
// tj:   2867200  4096
// wt:   3297280  114688   conv weights (I,K,O)
// tlwT: 3411968  65536    temp_lin_w transposed
// flwT: 3477504  40000    feat_lin_w transposed

__global__ void k_prep(const float* __restrict__ cw, const float* __restrict__ tlw,
                       const float* __restrict__ flw, float* __restrict__ wt,
                       float* __restrict__ tlwT, float* __restrict__ flwT) {
    int id = blockIdx.x * 256 + threadIdx.x;
    if (id < KS * FF * FF) {
        int o = id & (FF - 1);
        int r = id >> 7;
        int k = r % KS;
        int i = r / KS;
        wt[id] = cw[(o * FF + i) * KS + k];
    }
    if (id < ET * ET) {
        int e = id & (ET - 1);
        int d = id >> 8;
        tlwT[id] = tlw[e * ET + d];
    }
    if (id < EF * EF) {
        int e = id % EF;
        int d = id / EF;
        flwT[id] = flw[e * EF + d];
    }
}

// K1: Conv1d 'same' + relu, pos-encode fused into staging. (unchanged)
#define CTW 10
#define NROW 16
#define XPAD 20
__global__ __launch_bounds__(512) void k_conv(const float* __restrict__ x,
                                              const float* __restrict__ wt,
                                              const float* __restrict__ cb,
                                              float* __restrict__ x2) {
    int b = blockIdx.x & 31;
    int tile = blockIdx.x >> 5;
    int w0 = tile * CTW;
    int tid = threadIdx.x;
    int o = tid & (FF - 1);
    int h = tid >> 7;
    __shared__ float xs[FF][XPAD];
    __shared__ float part[4][CTW][FF];
    for (int idx = tid; idx < NROW * FF; idx += 512) {
        int r = idx >> 7, f = idx & (FF - 1);
        int t = w0 - 3 + r;
        float v = 0.f;
        if ((unsigned)t < WW) {
            float div = __expf((float)f * (-9.210340371976184f / (float)FF));
            float arg = (float)t * div;
            v = x[(b * WW + t) * FF + f] + __sinf(arg) + __cosf(arg);
        }
        xs[f][r] = v;
    }
    __syncthreads();
    float acc[CTW];
#pragma unroll
    for (int t = 0; t < CTW; ++t) acc[t] = 0.f;
    const float* wbase = wt + (h * 32) * KS * FF + o;
#pragma unroll 2
    for (int il = 0; il < 32; ++il) {
        int i = h * 32 + il;
        float4 X0 = *(const float4*)&xs[i][0];
        float4 X1 = *(const float4*)&xs[i][4];
        float4 X2 = *(const float4*)&xs[i][8];
        float4 X3 = *(const float4*)&xs[i][12];
        float xr[16] = {X0.x, X0.y, X0.z, X0.w, X1.x, X1.y, X1.z, X1.w,
                        X2.x, X2.y, X2.z, X2.w, X3.x, X3.y, X3.z, X3.w};
        const float* wp = wbase + il * KS * FF;
#pragma unroll
        for (int k = 0; k < KS; ++k) {
            float wv = wp[k * FF];
#pragma unroll
            for (int t = 0; t < CTW; ++t) acc[t] += xr[t + k] * wv;
        }
    }
#pragma unroll
    for (int t = 0; t < CTW; ++t) part[h][t][o] = acc[t];
    __syncthreads();
    for (int idx = tid; idx < CTW * FF; idx += 512) {
        int t = idx >> 7, oo = idx & (FF - 1);
        float s = part[0][t][oo] + part[1][t][oo] + part[2][t][oo] +
                  part[3][t][oo] + cb[oo];
        x2[(b * WW + w0 + t) * FF + oo] = fmaxf(s, 0.f);
    }
}

// K2: temporal L/R GEMM. (unchanged)
__global__ __launch_bounds__(512) void k_lr_t(const float* __restrict__ x2,
                                              const float* __restrict__ tlwT,
                                              const float* __restrict__ tlb,
                                              float* __restrict__ LT,
                                              float* __restrict__ Rt) {
    int b = blockIdx.x & 31;
    int tile = blockIdx.x >> 5;
    int i0 = tile * 8;
    int tid = threadIdx.x;
    int e = tid & 255;
    int rh = tid >> 8;
    __shared__ float xs[8][FF];
    for (int idx = tid; idx < 8 * FF; idx += 512) {
        int r = idx >> 7, d = idx & (FF - 1);
        int row = i0 + r; if (row >= WW) row = WW - 1;
        xs[r][d] = x2[(b * WW + row) * FF + d];
    }
    __syncthreads();
    float aL[4] = {0, 0, 0, 0}, aR[4] = {0, 0, 0, 0};
    const float* wl = tlwT + e;
#pragma unroll 2
    for (int dc = 0; dc < 32; ++dc) {
        float xv[4][4];
#pragma unroll
        for (int r = 0; r < 4; ++r)
            *(float4*)xv[r] = *(const float4*)&xs[rh * 4 + r][dc * 4];
#pragma unroll
        for (int q = 0; q < 4; ++q) {
            int d = dc * 4 + q;
            float wL = wl[d * ET];
            float wR = wl[(FF + d) * ET];
#pragma unroll
            for (int r = 0; r < 4; ++r) {
                aL[r] += xv[r][q] * wL;
                aR[r] += xv[r][q] * wR;
            }
        }
    }
    int ibase = i0 + rh * 4;
    if (ibase < WW) {
        float lb = tlb[e];
        float o0[4];
#pragma unroll
        for (int r = 0; r < 4; ++r) o0[r] = aL[r] + lb;
        *(float4*)&LT[(b * ET + e) * WW + ibase] = *(float4*)o0;
        *(float4*)&Rt[(b * ET + e) * WW + ibase] = *(float4*)aR;
    }
}

// K3: temporal attention, QT=4, LDS-staged score+PV, grid 800 (3.1 blk/CU).
__global__ __launch_bounds__(256) void k_att_t(const float* __restrict__ LT,
                                               const float* __restrict__ Rt,
                                               const float* __restrict__ ta,
                                               const float* __restrict__ tbias,
                                               const float* __restrict__ x2,
                                               float* __restrict__ x3T) {
    int b = blockIdx.x & 31;
    int tile = blockIdx.x >> 5;   // 0..24
    int i0 = tile * 4;
    int tid = threadIdx.x;
    int j = tid & 127, q = tid >> 7;
    __shared__ float Rs[32][FF];      // 16KB, reused for x2 in PV
    __shared__ float Ls[32][4];
    __shared__ float tas[ET];
    __shared__ float attQ[4][FF];     // [query][j] -> conflict-free writes
    __shared__ float ob[4][FF];
    __shared__ float redA[4][2], redB[4][2];
    tas[tid] = ta[tid];               // 256 == ET
    float s[2] = {0.f, 0.f};
    for (int ch = 0; ch < 8; ++ch) {
        int e0 = ch * 32;
#pragma unroll
        for (int it = 0; it < 16; ++it) {
            int idx = tid + it * 256;
            int er = idx >> 7, w = idx & 127;
            Rs[er][w] = (w < WW) ? Rt[(b * ET + e0 + er) * WW + w] : 0.f;
        }
        if (tid < 128) {
            int er = tid >> 2, qq = tid & 3;
            Ls[er][qq] = LT[(b * ET + e0 + er) * WW + i0 + qq];
        }
        __syncthreads();
#pragma unroll 8
        for (int e = 0; e < 32; ++e) {
            float rj = Rs[e][j];
            float ae = tas[e0 + e];
            float2 lv = *(const float2*)&Ls[e][q * 2];
            float v;
            v = lv.x + rj; v = fmaxf(v, 0.2f * v); s[0] += v * ae;
            v = lv.y + rj; v = fmaxf(v, 0.2f * v); s[1] += v * ae;
        }
        __syncthreads();
    }
    float ej[2];
#pragma unroll
    for (int ii = 0; ii < 2; ++ii) {
        int i = i0 + q * 2 + ii;
        float bv = (j < WW) ? tbias[i * WW + j] : 0.f;
        ej[ii] = (j < WW) ? s[ii] + bv : -1e30f;
    }
    float m[2] = {ej[0], ej[1]};
#pragma unroll
    for (int off = 32; off > 0; off >>= 1) {
#pragma unroll
        for (int ii = 0; ii < 2; ++ii) m[ii] = fmaxf(m[ii], __shfl_xor(m[ii], off));
    }
    int wv = tid >> 6;
    if ((tid & 63) == 0) { redA[wv][0] = m[0]; redA[wv][1] = m[1]; }
    __syncthreads();
    float p[2], ps[2];
#pragma unroll
    for (int ii = 0; ii < 2; ++ii) {
        float mx = fmaxf(redA[wv][ii], redA[wv ^ 1][ii]);
        p[ii] = (j < WW) ? __expf(ej[ii] - mx) : 0.f;
        ps[ii] = p[ii];
    }
#pragma unroll
    for (int off = 32; off > 0; off >>= 1) {
#pragma unroll
        for (int ii = 0; ii < 2; ++ii) ps[ii] += __shfl_xor(ps[ii], off);
    }
    if ((tid & 63) == 0) { redB[wv][0] = ps[0]; redB[wv][1] = ps[1]; }
    __syncthreads();
#pragma unroll
    for (int ii = 0; ii < 2; ++ii) {
        float inv = 1.f / (redB[wv][ii] + redB[wv ^ 1][ii]);
        attQ[q * 2 + ii][j] = p[ii] * inv;
    }
    // PV: x2 staged in 4 chunks of 25 rows; threads = d(128) x ph(2)
    int d = tid & 127, ph = tid >> 7;
    float pv[2] = {0.f, 0.f};
    const float* a0 = attQ[ph * 2];
    const float* a1 = attQ[ph * 2 + 1];
    for (int jc = 0; jc < 4; ++jc) {
        __syncthreads();
        for (int idx = tid; idx < 25 * FF; idx += 256) {
            int r = idx >> 7, f = idx & 127;
            Rs[r][f] = x2[(b * WW + jc * 25 + r) * FF + f];
        }
        __syncthreads();
#pragma unroll 5
        for (int r = 0; r < 25; ++r) {
            float xv = Rs[r][d];
            pv[0] += a0[jc * 25 + r] * xv;
            pv[1] += a1[jc * 25 + r] * xv;
        }
    }
    ob[ph * 2][d] = tanhf(pv[0]);
    ob[ph * 2 + 1][d] = tanhf(pv[1]);
    __syncthreads();
    if (tid < FF) {
        float4 v = make_float4(ob[0][tid], ob[1][tid], ob[2][tid], ob[3][tid]);
        *(float4*)&x3T[(b * FF + tid) * WW + i0] = v;   // 25*4 == 100, exact
    }
}

// K4: feature L/R GEMM. (unchanged)
__global__ __launch_bounds__(512) void k_lr_f(const float* __restrict__ x3T,
                                              const float* __restrict__ flwT,
                                              const float* __restrict__ flb,
                                              float* __restrict__ LfT,
                                              float* __restrict__ RfT) {
    int b = blockIdx.x & 31;
    int tile = blockIdx.x >> 5;
    int f0 = tile * 8;
    int tid = threadIdx.x;
    int e = tid & 255;
    int rh = tid >> 8;
    __shared__ float xs[8][WW];
    for (int idx = tid; idx < 8 * WW; idx += 512) {
        int r = idx / WW, d = idx % WW;
        xs[r][d] = x3T[(b * FF + f0 + r) * WW + d];
    }
    __syncthreads();
    if (e < EF) {
        float aL[4] = {0, 0, 0, 0}, aR[4] = {0, 0, 0, 0};
        const float* wl = flwT + e;
#pragma unroll 2
        for (int dc = 0; dc < 25; ++dc) {
            float xv[4][4];
#pragma unroll
            for (int r = 0; r < 4; ++r)
                *(float4*)xv[r] = *(const float4*)&xs[rh * 4 + r][dc * 4];
#pragma unroll
            for (int q = 0; q < 4; ++q) {
                int d = dc * 4 + q;
                float wL = wl[d * EF];
                float wR = wl[(WW + d) * EF];
#pragma unroll
                for (int r = 0; r < 4; ++r) {
                    aL[r] += xv[r][q] * wL;
                    aR[r] += xv[r][q] * wR;
                }
            }
        }
        float lb = flb[e];
        float o0[4];
#pragma unroll
        for (int r = 0; r < 4; ++r) o0[r] = aL[r] + lb;
        int fbase = f0 + rh * 4;
        *(float4*)&LfT[(b * EF + e) * FF + fbase] = *(float4*)o0;
        *(float4*)&RfT[(b * EF + e) * FF + fbase] = *(float4*)aR;
    }
}

// K5: feature attention, QT=4, LDS-staged, grid 1024 (4 blk/CU), fused tj.
__global__ __launch_bounds__(256) void k_att_f(const float* __restrict__ LfT,
                                               const float* __restrict__ RfT,
                                               const float* __restrict__ fa,
                                               const float* __restrict__ fbias,
                                               const float* __restrict__ x3T,
                                               const float* __restrict__ fcw,
                                               float* __restrict__ tj) {
    int b = blockIdx.x & 31;
    int tile = blockIdx.x >> 5;   // 0..31
    int f0 = tile * 4;
    int tid = threadIdx.x;
    int j = tid & 127, q = tid >> 7;
    __shared__ float Rs[32][FF];      // score uses 25 rows; PV uses 32
    __shared__ float Ls[25][4];
    __shared__ float fas[EF];
    __shared__ float attQ[4][FF];
    __shared__ float redA[4][2], redB[4][2], redT[4][2];
    if (tid < EF) fas[tid] = fa[tid];
    float s[2] = {0.f, 0.f};
    for (int ch = 0; ch < 8; ++ch) {
        int e0 = ch * 25;
        for (int idx = tid; idx < 25 * FF; idx += 256) {
            int er = idx >> 7, f = idx & 127;
            Rs[er][f] = RfT[(b * EF + e0 + er) * FF + f];
        }
        if (tid < 100) {
            int er = tid >> 2, qq = tid & 3;
            Ls[er][qq] = LfT[(b * EF + e0 + er) * FF + f0 + qq];
        }
        __syncthreads();
#pragma unroll 5
        for (int e = 0; e < 25; ++e) {
            float rj = Rs[e][j];
            float ae = fas[e0 + e];
            float2 lv = *(const float2*)&Ls[e][q * 2];
            float v;
            v = lv.x + rj; v = fmaxf(v, 0.2f * v); s[0] += v * ae;
            v = lv.y + rj; v = fmaxf(v, 0.2f * v); s[1] += v * ae;
        }
        __syncthreads();
    }
    float ej[2] = {s[0] + fbias[(f0 + q * 2) * FF + j],
                   s[1] + fbias[(f0 + q * 2 + 1) * FF + j]};
    float m[2] = {ej[0], ej[1]};
#pragma unroll
    for (int off = 32; off > 0; off >>= 1) {
#pragma unroll
        for (int ii = 0; ii < 2; ++ii) m[ii] = fmaxf(m[ii], __shfl_xor(m[ii], off));
    }
    int wv = tid >> 6;
    if ((tid & 63) == 0) { redA[wv][0] = m[0]; redA[wv][1] = m[1]; }
    __syncthreads();
    float p[2], ps[2];
#pragma unroll
    for (int ii = 0; ii < 2; ++ii) {
        float mx = fmaxf(redA[wv][ii], redA[wv ^ 1][ii]);
        p[ii] = __expf(ej[ii] - mx);
        ps[ii] = p[ii];
    }
#pragma unroll
    for (int off = 32; off > 0; off >>= 1) {
#pragma unroll
        for (int ii = 0; ii < 2; ++ii) ps[ii] += __shfl_xor(ps[ii], off);
    }
    if ((tid & 63) == 0) { redB[wv][0] = ps[0]; redB[wv][1] = ps[1]; }
    __syncthreads();
#pragma unroll
    for (int ii = 0; ii < 2; ++ii) {
        float inv = 1.f / (redB[wv][ii] + redB[wv ^ 1][ii]);
        attQ[q * 2 + ii][j] = p[ii] * inv;
    }
    // PV: x3T staged in 4 chunks of 32 rows; threads = w(128) x ph(2)
    int w = tid & 127, ph = tid >> 7;
    float pv[2] = {0.f, 0.f};
    const float* a0 = attQ[ph * 2];
    const float* a1 = attQ[ph * 2 + 1];
    for (int jc = 0; jc < 4; ++jc) {
        __syncthreads();
#pragma unroll
        for (int it = 0; it < 16; ++it) {
            int idx = tid + it * 256;
            int r = idx >> 7, ww = idx & 127;
            Rs[r][ww] = (ww < WW) ? x3T[(b * FF + jc * 32 + r) * WW + ww] : 0.f;
        }
        __syncthreads();
#pragma unroll 8
        for (int r = 0; r < 32; ++r) {
            float xv = Rs[r][w];
            pv[0] += a0[jc * 32 + r] * xv;
            pv[1] += a1[jc * 32 + r] * xv;
        }
    }
    bool wok = (w < WW);
    float fcv = wok ? fcw[w] : 0.f;
    float tv[2] = {tanhf(pv[0]) * fcv, tanhf(pv[1]) * fcv};
#pragma unroll
    for (int off = 32; off > 0; off >>= 1) {
#pragma unroll
        for (int ii = 0; ii < 2; ++ii) tv[ii] += __shfl_xor(tv[ii], off);
    }
    if ((tid & 63) == 0) { redT[wv][0] = tv[0]; redT[wv][1] = tv[1]; }
    __syncthreads();
    if (tid < 4) {
        int hh = tid >> 1, ii = tid & 1;   // hh = ph, query = hh*2+ii
        tj[b * FF + f0 + hh * 2 + ii] = redT[hh * 2][ii] + redT[hh * 2 + 1][ii];
    }
}

// K6: out[b,f] = tanh(sum_j cos(f,j)*tj[b,j] + fcb). (unchanged)
__global__ __launch_bounds__(128) void k_fc(const float* __restrict__ tjg,
                                            const float* __restrict__ emb,
                                            const float* __restrict__ fcb,
                                            float* __restrict__ out) {
    int b = blockIdx.x;
    int f = threadIdx.x;
    __shared__ float en[FF][12];
    __shared__ float tjs[FF];
    {
        float4 e0 = *(const float4*)&emb[f * 8];
        float4 e1 = *(const float4*)&emb[f * 8 + 4];
        float n = e0.x*e0.x + e0.y*e0.y + e0.z*e0.z + e0.w*e0.w +
                  e1.x*e1.x + e1.y*e1.y + e1.z*e1.z + e1.w*e1.w;
        float rin = rsqrtf(n);
        float4 a = make_float4(e0.x*rin, e0.y*rin, e0.z*rin, e0.w*rin);
        float4 c = make_float4(e1.x*rin, e1.y*rin, e1.z*rin, e1.w*rin);
        *(float4*)&en[f][0] = a;
        *(float4*)&en[f][4] = c;
        tjs[f] = tjg[b * FF + f];
    }
    __syncthreads();
    float er[8];
#pragma unroll
    for (int k = 0; k < 8; ++k) er[k] = en[f][k];
    float acc = fcb[0];
    for (int jj = 0; jj < FF; ++jj) {
        float4 a = *(const float4*)&en[jj][0];
        float4 c = *(const float4*)&en[jj][4];
        float d8 = er[0]*a.x + er[1]*a.y + er[2]*a.z + er[3]*a.w +
                   er[4]*c.x + er[5]*c.y + er[6]*c.z + er[7]*c.w;
        acc += d8 * tjs[jj];
    }
    out[b * FF + f] = tanhf(acc);
}

extern "C" void kernel_launch(void* const* d_in, const int* in_sizes, int n_in,
                              void* d_out, int out_size, void* d_ws, size_t ws_size,
                              hipStream_t stream) {
    const float* x     = (const float*)d_in[0];
    const float* cw    = (const float*)d_in[1];
    const float* cb    = (const float*)d_in[2];
    const float* tlw   = (const float*)d_in[3];
    const float* tlb   = (const float*)d_in[4];
    const float* ta    = (const float*)d_in[5];
    const float* tbias = (const float*)d_in[6];
    const float* flw   = (const float*)d_in[7];
    const float* flb   = (const float*)d_in[8];
    const float* fa    = (const float*)d_in[9];
    const float* fbias = (const float*)d_in[10];
    const float* emb   = (const float*)d_in[11];
    const float* fcw   = (const float*)d_in[12];
    const float* fcb   = (const float*)d_in[13];
    float* out = (float*)d_out;
    float* ws = (float*)d_ws;

    float* x2   = ws + 409600;
    float* x3T  = ws + 819200;
    float* LT   = ws + 1228800;   // reused as LfT
    float* Rt   = ws + 2048000;   // reused as RfT
    float* tj   = ws + 2867200;
    float* wt   = ws + 3297280;
    float* tlwT = ws + 3411968;
    float* flwT = ws + 3477504;

    k_prep<<<448, 256, 0, stream>>>(cw, tlw, flw, wt, tlwT, flwT);
    k_conv<<<BB * 10, 512, 0, stream>>>(x, wt, cb, x2);
    k_lr_t<<<BB * 13, 512, 0, stream>>>(x2, tlwT, tlb, LT, Rt);
    k_att_t<<<BB * 25, 256, 0, stream>>>(LT, Rt, ta, tbias, x2, x3T);
    k_lr_f<<<BB * 16, 512, 0, stream>>>(x3T, flwT, flb, LT, Rt);
    k_att_f<<<BB * 32, 256, 0, stream>>>(LT, Rt, fa, fbias, x3T, fcw, tj);
    k_fc<<<BB, 128, 0, stream>>>(tj, emb, fcb, out);
}

// Round 10
// 127.557 us; speedup vs baseline: 1.3537x; 1.1064x over previous
//
#include <hip/hip_runtime.h>
#include <math.h>

#define BB 32
#define WW 100
#define FF 128
#define KS 7
#define ET 256   // 2F (temporal GAT embed)
#define EF 200   // 2W (feature GAT embed)

// b = blockIdx & 31 (b-minor): BB=32 ≡ 0 mod 8 XCDs -> all tiles of batch b
// land on one XCD; per-b panels are HBM-fetched once, then L2-served.

// ---------------- workspace layout (floats) ----------------
// x2:   409600   409600   conv output (B,W,F)
// x3T:  819200   409600   temporal GAT output, TRANSPOSED (B,F,W)
// LT:   1228800  819200   temporal left TRANSPOSED (B,256,100) -> reused LfT (B,200,128)
// Rt:   2048000  819200   temporal right TRANSPOSED (B,256,100) -> reused RfT (B,200,128)
// tj:   2867200  4096
// wt:   3297280  114688   conv weights (I,K,O)
// tlwT: 3411968  65536    temp_lin_w transposed
// flwT: 3477504  40000    feat_lin_w transposed

__global__ void k_prep(const float* __restrict__ cw, const float* __restrict__ tlw,
                       const float* __restrict__ flw, float* __restrict__ wt,
                       float* __restrict__ tlwT, float* __restrict__ flwT) {
    int id = blockIdx.x * 256 + threadIdx.x;
    if (id < KS * FF * FF) {
        int o = id & (FF - 1);
        int r = id >> 7;
        int k = r % KS;
        int i = r / KS;
        wt[id] = cw[(o * FF + i) * KS + k];
    }
    if (id < ET * ET) {
        int e = id & (ET - 1);
        int d = id >> 8;
        tlwT[id] = tlw[e * ET + d];
    }
    if (id < EF * EF) {
        int e = id % EF;
        int d = id / EF;
        flwT[id] = flw[e * EF + d];
    }
}

// K1: Conv1d 'same' + relu, pos-encode fused into staging. (unchanged)
#define CTW 10
#define NROW 16
#define XPAD 20
__global__ __launch_bounds__(512) void k_conv(const float* __restrict__ x,
                                              const float* __restrict__ wt,
                                              const float* __restrict__ cb,
                                              float* __restrict__ x2) {
    int b = blockIdx.x & 31;
    int tile = blockIdx.x >> 5;
    int w0 = tile * CTW;
    int tid = threadIdx.x;
    int o = tid & (FF - 1);
    int h = tid >> 7;
    __shared__ float xs[FF][XPAD];
    __shared__ float part[4][CTW][FF];
    for (int idx = tid; idx < NROW * FF; idx += 512) {
        int r = idx >> 7, f = idx & (FF - 1);
        int t = w0 - 3 + r;
        float v = 0.f;
        if ((unsigned)t < WW) {
            float div = __expf((float)f * (-9.210340371976184f / (float)FF));
            float arg = (float)t * div;
            v = x[(b * WW + t) * FF + f] + __sinf(arg) + __cosf(arg);
        }
        xs[f][r] = v;
    }
    __syncthreads();
    float acc[CTW];
#pragma unroll
    for (int t = 0; t < CTW; ++t) acc[t] = 0.f;
    const float* wbase = wt + (h * 32) * KS * FF + o;
#pragma unroll 2
    for (int il = 0; il < 32; ++il) {
        int i = h * 32 + il;
        float4 X0 = *(const float4*)&xs[i][0];
        float4 X1 = *(const float4*)&xs[i][4];
        float4 X2 = *(const float4*)&xs[i][8];
        float4 X3 = *(const float4*)&xs[i][12];
        float xr[16] = {X0.x, X0.y, X0.z, X0.w, X1.x, X1.y, X1.z, X1.w,
                        X2.x, X2.y, X2.z, X2.w, X3.x, X3.y, X3.z, X3.w};
        const float* wp = wbase + il * KS * FF;
#pragma unroll
        for (int k = 0; k < KS; ++k) {
            float wv = wp[k * FF];
#pragma unroll
            for (int t = 0; t < CTW; ++t) acc[t] += xr[t + k] * wv;
        }
    }
#pragma unroll
    for (int t = 0; t < CTW; ++t) part[h][t][o] = acc[t];
    __syncthreads();
    for (int idx = tid; idx < CTW * FF; idx += 512) {
        int t = idx >> 7, oo = idx & (FF - 1);
        float s = part[0][t][oo] + part[1][t][oo] + part[2][t][oo] +
                  part[3][t][oo] + cb[oo];
        x2[(b * WW + w0 + t) * FF + oo] = fmaxf(s, 0.f);
    }
}

// K2: temporal L/R GEMM. (unchanged)
__global__ __launch_bounds__(512) void k_lr_t(const float* __restrict__ x2,
                                              const float* __restrict__ tlwT,
                                              const float* __restrict__ tlb,
                                              float* __restrict__ LT,
                                              float* __restrict__ Rt) {
    int b = blockIdx.x & 31;
    int tile = blockIdx.x >> 5;
    int i0 = tile * 8;
    int tid = threadIdx.x;
    int e = tid & 255;
    int rh = tid >> 8;
    __shared__ float xs[8][FF];
    for (int idx = tid; idx < 8 * FF; idx += 512) {
        int r = idx >> 7, d = idx & (FF - 1);
        int row = i0 + r; if (row >= WW) row = WW - 1;
        xs[r][d] = x2[(b * WW + row) * FF + d];
    }
    __syncthreads();
    float aL[4] = {0, 0, 0, 0}, aR[4] = {0, 0, 0, 0};
    const float* wl = tlwT + e;
#pragma unroll 2
    for (int dc = 0; dc < 32; ++dc) {
        float xv[4][4];
#pragma unroll
        for (int r = 0; r < 4; ++r)
            *(float4*)xv[r] = *(const float4*)&xs[rh * 4 + r][dc * 4];
#pragma unroll
        for (int q = 0; q < 4; ++q) {
            int d = dc * 4 + q;
            float wL = wl[d * ET];
            float wR = wl[(FF + d) * ET];
#pragma unroll
            for (int r = 0; r < 4; ++r) {
                aL[r] += xv[r][q] * wL;
                aR[r] += xv[r][q] * wR;
            }
        }
    }
    int ibase = i0 + rh * 4;
    if (ibase < WW) {
        float lb = tlb[e];
        float o0[4];
#pragma unroll
        for (int r = 0; r < 4; ++r) o0[r] = aL[r] + lb;
        *(float4*)&LT[(b * ET + e) * WW + ibase] = *(float4*)o0;
        *(float4*)&Rt[(b * ET + e) * WW + ibase] = *(float4*)aR;
    }
}

// K3: temporal attention. QT=8, 512 thr (8 waves), grid 416 = 3.25 waves/SIMD.
// Score: j(128) x g(4), 2 queries each. PV: d(128) x ph(4), 2 queries each.
__global__ __launch_bounds__(512) void k_att_t(const float* __restrict__ LT,
                                               const float* __restrict__ Rt,
                                               const float* __restrict__ ta,
                                               const float* __restrict__ tbias,
                                               const float* __restrict__ x2,
                                               float* __restrict__ x3T) {
    int b = blockIdx.x & 31;
    int tile = blockIdx.x >> 5;   // 0..12
    int i0 = tile * 8;
    int tid = threadIdx.x;
    int j = tid & 127, g = tid >> 7;
    __shared__ float Rs[32][FF];      // reused for x2 in PV
    __shared__ float Ls[32][8];
    __shared__ float tas[ET];
    __shared__ float attQ[8][FF];
    __shared__ float ob[8][FF];
    __shared__ float redA[8][2], redB[8][2];
    if (tid < ET) tas[tid] = ta[tid];
    float s0 = 0.f, s1 = 0.f;
    for (int ch = 0; ch < 8; ++ch) {
        int e0 = ch * 32;
#pragma unroll
        for (int it = 0; it < 8; ++it) {
            int idx = tid + it * 512;
            int er = idx >> 7, w = idx & 127;
            Rs[er][w] = (w < WW) ? Rt[(b * ET + e0 + er) * WW + w] : 0.f;
        }
        if (tid < 256) {
            int er = tid >> 3, qq = tid & 7;
            int row = i0 + qq; if (row >= WW) row = WW - 1;
            Ls[er][qq] = LT[(b * ET + e0 + er) * WW + row];
        }
        __syncthreads();
#pragma unroll 8
        for (int e = 0; e < 32; ++e) {
            float rj = Rs[e][j];
            float ae = tas[e0 + e];
            float2 lv = *(const float2*)&Ls[e][g * 2];
            float v;
            v = lv.x + rj; v = fmaxf(v, 0.2f * v); s0 += v * ae;
            v = lv.y + rj; v = fmaxf(v, 0.2f * v); s1 += v * ae;
        }
        __syncthreads();
    }
    float ej[2];
#pragma unroll
    for (int ii = 0; ii < 2; ++ii) {
        int i = i0 + g * 2 + ii;
        float sv = (ii == 0) ? s0 : s1;
        float bv = (j < WW && i < WW) ? tbias[i * WW + j] : 0.f;
        ej[ii] = (j < WW && i < WW) ? sv + bv : -1e30f;
    }
    float m[2] = {ej[0], ej[1]};
#pragma unroll
    for (int off = 32; off > 0; off >>= 1) {
#pragma unroll
        for (int ii = 0; ii < 2; ++ii) m[ii] = fmaxf(m[ii], __shfl_xor(m[ii], off));
    }
    int wv = tid >> 6;   // wave 0..7; waves 2g, 2g+1 share query group g
    if ((tid & 63) == 0) { redA[wv][0] = m[0]; redA[wv][1] = m[1]; }
    __syncthreads();
    float p[2], ps[2];
#pragma unroll
    for (int ii = 0; ii < 2; ++ii) {
        float mx = fmaxf(redA[g * 2][ii], redA[g * 2 + 1][ii]);
        p[ii] = (j < WW) ? __expf(ej[ii] - mx) : 0.f;
        ps[ii] = p[ii];
    }
#pragma unroll
    for (int off = 32; off > 0; off >>= 1) {
#pragma unroll
        for (int ii = 0; ii < 2; ++ii) ps[ii] += __shfl_xor(ps[ii], off);
    }
    if ((tid & 63) == 0) { redB[wv][0] = ps[0]; redB[wv][1] = ps[1]; }
    __syncthreads();
#pragma unroll
    for (int ii = 0; ii < 2; ++ii) {
        float inv = 1.f / (redB[g * 2][ii] + redB[g * 2 + 1][ii]);
        attQ[g * 2 + ii][j] = p[ii] * inv;
    }
    // PV: x2 staged in 4 chunks of 25 rows; threads = d(128) x ph(4)
    int d = tid & 127, ph = tid >> 7;
    float pv0 = 0.f, pv1 = 0.f;
    const float* a0 = attQ[ph * 2];
    const float* a1 = attQ[ph * 2 + 1];
    for (int jc = 0; jc < 4; ++jc) {
        __syncthreads();
        for (int idx = tid; idx < 25 * FF; idx += 512) {
            int r = idx >> 7, f = idx & 127;
            Rs[r][f] = x2[(b * WW + jc * 25 + r) * FF + f];
        }
        __syncthreads();
#pragma unroll 5
        for (int r = 0; r < 25; ++r) {
            float xv = Rs[r][d];
            pv0 += a0[jc * 25 + r] * xv;
            pv1 += a1[jc * 25 + r] * xv;
        }
    }
    ob[ph * 2][d] = tanhf(pv0);
    ob[ph * 2 + 1][d] = tanhf(pv1);
    __syncthreads();
    if (tid < 256) {
        int f = tid >> 1, half = tid & 1;
        if (i0 + half * 4 < WW) {
            float4 v = make_float4(ob[half * 4][f], ob[half * 4 + 1][f],
                                   ob[half * 4 + 2][f], ob[half * 4 + 3][f]);
            *(float4*)&x3T[(b * FF + f) * WW + i0 + half * 4] = v;
        }
    }
}

// K4: feature L/R GEMM. (unchanged)
__global__ __launch_bounds__(512) void k_lr_f(const float* __restrict__ x3T,
                                              const float* __restrict__ flwT,
                                              const float* __restrict__ flb,
                                              float* __restrict__ LfT,
                                              float* __restrict__ RfT) {
    int b = blockIdx.x & 31;
    int tile = blockIdx.x >> 5;
    int f0 = tile * 8;
    int tid = threadIdx.x;
    int e = tid & 255;
    int rh = tid >> 8;
    __shared__ float xs[8][WW];
    for (int idx = tid; idx < 8 * WW; idx += 512) {
        int r = idx / WW, d = idx % WW;
        xs[r][d] = x3T[(b * FF + f0 + r) * WW + d];
    }
    __syncthreads();
    if (e < EF) {
        float aL[4] = {0, 0, 0, 0}, aR[4] = {0, 0, 0, 0};
        const float* wl = flwT + e;
#pragma unroll 2
        for (int dc = 0; dc < 25; ++dc) {
            float xv[4][4];
#pragma unroll
            for (int r = 0; r < 4; ++r)
                *(float4*)xv[r] = *(const float4*)&xs[rh * 4 + r][dc * 4];
#pragma unroll
            for (int q = 0; q < 4; ++q) {
                int d = dc * 4 + q;
                float wL = wl[d * EF];
                float wR = wl[(WW + d) * EF];
#pragma unroll
                for (int r = 0; r < 4; ++r) {
                    aL[r] += xv[r][q] * wL;
                    aR[r] += xv[r][q] * wR;
                }
            }
        }
        float lb = flb[e];
        float o0[4];
#pragma unroll
        for (int r = 0; r < 4; ++r) o0[r] = aL[r] + lb;
        int fbase = f0 + rh * 4;
        *(float4*)&LfT[(b * EF + e) * FF + fbase] = *(float4*)o0;
        *(float4*)&RfT[(b * EF + e) * FF + fbase] = *(float4*)aR;
    }
}

// K5: feature attention. QT=8, 512 thr, grid 512 = 4 waves/SIMD, fused tj.
__global__ __launch_bounds__(512) void k_att_f(const float* __restrict__ LfT,
                                               const float* __restrict__ RfT,
                                               const float* __restrict__ fa,
                                               const float* __restrict__ fbias,
                                               const float* __restrict__ x3T,
                                               const float* __restrict__ fcw,
                                               float* __restrict__ tj) {
    int b = blockIdx.x & 31;
    int tile = blockIdx.x >> 5;   // 0..15
    int f0 = tile * 8;
    int tid = threadIdx.x;
    int j = tid & 127, g = tid >> 7;
    __shared__ float Rs[32][FF];      // score uses 25 rows; PV uses 32
    __shared__ float Ls[25][8];
    __shared__ float fas[EF];
    __shared__ float attQ[8][FF];
    __shared__ float redA[8][2], redB[8][2], redT[8][2];
    if (tid < EF) fas[tid] = fa[tid];
    float s0 = 0.f, s1 = 0.f;
    for (int ch = 0; ch < 8; ++ch) {
        int e0 = ch * 25;
        for (int idx = tid; idx < 25 * FF; idx += 512) {
            int er = idx >> 7, f = idx & 127;
            Rs[er][f] = RfT[(b * EF + e0 + er) * FF + f];
        }
        if (tid < 200) {
            int er = tid >> 3, qq = tid & 7;
            Ls[er][qq] = LfT[(b * EF + e0 + er) * FF + f0 + qq];
        }
        __syncthreads();
#pragma unroll 5
        for (int e = 0; e < 25; ++e) {
            float rj = Rs[e][j];
            float ae = fas[e0 + e];
            float2 lv = *(const float2*)&Ls[e][g * 2];
            float v;
            v = lv.x + rj; v = fmaxf(v, 0.2f * v); s0 += v * ae;
            v = lv.y + rj; v = fmaxf(v, 0.2f * v); s1 += v * ae;
        }
        __syncthreads();
    }
    float ej[2] = {s0 + fbias[(f0 + g * 2) * FF + j],
                   s1 + fbias[(f0 + g * 2 + 1) * FF + j]};
    float m[2] = {ej[0], ej[1]};
#pragma unroll
    for (int off = 32; off > 0; off >>= 1) {
#pragma unroll
        for (int ii = 0; ii < 2; ++ii) m[ii] = fmaxf(m[ii], __shfl_xor(m[ii], off));
    }
    int wv = tid >> 6;
    if ((tid & 63) == 0) { redA[wv][0] = m[0]; redA[wv][1] = m[1]; }
    __syncthreads();
    float p[2], ps[2];
#pragma unroll
    for (int ii = 0; ii < 2; ++ii) {
        float mx = fmaxf(redA[g * 2][ii], redA[g * 2 + 1][ii]);
        p[ii] = __expf(ej[ii] - mx);
        ps[ii] = p[ii];
    }
#pragma unroll
    for (int off = 32; off > 0; off >>= 1) {
#pragma unroll
        for (int ii = 0; ii < 2; ++ii) ps[ii] += __shfl_xor(ps[ii], off);
    }
    if ((tid & 63) == 0) { redB[wv][0] = ps[0]; redB[wv][1] = ps[1]; }
    __syncthreads();
#pragma unroll
    for (int ii = 0; ii < 2; ++ii) {
        float inv = 1.f / (redB[g * 2][ii] + redB[g * 2 + 1][ii]);
        attQ[g * 2 + ii][j] = p[ii] * inv;
    }
    // PV: x3T staged in 4 chunks of 32 rows; threads = w(128) x ph(4)
    int w = tid & 127, ph = tid >> 7;
    float pv0 = 0.f, pv1 = 0.f;
    const float* a0 = attQ[ph * 2];
    const float* a1 = attQ[ph * 2 + 1];
    for (int jc = 0; jc < 4; ++jc) {
        __syncthreads();
#pragma unroll
        for (int it = 0; it < 8; ++it) {
            int idx = tid + it * 512;
            int r = idx >> 7, ww = idx & 127;
            Rs[r][ww] = (ww < WW) ? x3T[(b * FF + jc * 32 + r) * WW + ww] : 0.f;
        }
        __syncthreads();
#pragma unroll 8
        for (int r = 0; r < 32; ++r) {
            float xv = Rs[r][w];
            pv0 += a0[jc * 32 + r] * xv;
            pv1 += a1[jc * 32 + r] * xv;
        }
    }
    bool wok = (w < WW);
    float fcv = wok ? fcw[w] : 0.f;
    float tv[2] = {tanhf(pv0) * fcv, tanhf(pv1) * fcv};
#pragma unroll
    for (int off = 32; off > 0; off >>= 1) {
#pragma unroll
        for (int ii = 0; ii < 2; ++ii) tv[ii] += __shfl_xor(tv[ii], off);
    }
    if ((tid & 63) == 0) { redT[wv][0] = tv[0]; redT[wv][1] = tv[1]; }
    __syncthreads();
    if (tid < 8) {
        int q = tid, php = q >> 1, ii = q & 1;
        tj[b * FF + f0 + q] = redT[php * 2][ii] + redT[php * 2 + 1][ii];
    }
}

// K6: out[b,f] = tanh(sum_j cos(f,j)*tj[b,j] + fcb). (unchanged)
__global__ __launch_bounds__(128) void k_fc(const float* __restrict__ tjg,
                                            const float* __restrict__ emb,
                                            const float* __restrict__ fcb,
                                            float* __restrict__ out) {
    int b = blockIdx.x;
    int f = threadIdx.x;
    __shared__ float en[FF][12];
    __shared__ float tjs[FF];
    {
        float4 e0 = *(const float4*)&emb[f * 8];
        float4 e1 = *(const float4*)&emb[f * 8 + 4];
        float n = e0.x*e0.x + e0.y*e0.y + e0.z*e0.z + e0.w*e0.w +
                  e1.x*e1.x + e1.y*e1.y + e1.z*e1.z + e1.w*e1.w;
        float rin = rsqrtf(n);
        float4 a = make_float4(e0.x*rin, e0.y*rin, e0.z*rin, e0.w*rin);
        float4 c = make_float4(e1.x*rin, e1.y*rin, e1.z*rin, e1.w*rin);
        *(float4*)&en[f][0] = a;
        *(float4*)&en[f][4] = c;
        tjs[f] = tjg[b * FF + f];
    }
    __syncthreads();
    float er[8];
#pragma unroll
    for (int k = 0; k < 8; ++k) er[k] = en[f][k];
    float acc = fcb[0];
    for (int jj = 0; jj < FF; ++jj) {
        float4 a = *(const float4*)&en[jj][0];
        float4 c = *(const float4*)&en[jj][4];
        float d8 = er[0]*a.x + er[1]*a.y + er[2]*a.z + er[3]*a.w +
                   er[4]*c.x + er[5]*c.y + er[6]*c.z + er[7]*c.w;
        acc += d8 * tjs[jj];
    }
    out[b * FF + f] = tanhf(acc);
}

extern "C" void kernel_launch(void* const* d_in, const int* in_sizes, int n_in,
                              void* d_out, int out_size, void* d_ws, size_t ws_size,
                              hipStream_t stream) {
    const float* x     = (const float*)d_in[0];
    const float* cw    = (const float*)d_in[1];
    const float* cb    = (const float*)d_in[2];
    const float* tlw   = (const float*)d_in[3];
    const float* tlb   = (const float*)d_in[4];
    const float* ta    = (const float*)d_in[5];
    const float* tbias = (const float*)d_in[6];
    const float* flw   = (const float*)d_in[7];
    const float* flb   = (const float*)d_in[8];
    const float* fa    = (const float*)d_in[9];
    const float* fbias = (const float*)d_in[10];
    const float* emb   = (const float*)d_in[11];
    const float* fcw   = (const float*)d_in[12];
    const float* fcb   = (const float*)d_in[13];
    float* out = (float*)d_out;
    float* ws = (float*)d_ws;

    float* x2   = ws + 409600;
    float* x3T  = ws + 819200;
    float* LT   = ws + 1228800;   // reused as LfT
    float* Rt   = ws + 2048000;   // reused as RfT
    float* tj   = ws + 2867200;
    float* wt   = ws + 3297280;
    float* tlwT = ws + 3411968;
    float* flwT = ws + 3477504;

    k_prep<<<448, 256, 0, stream>>>(cw, tlw, flw, wt, tlwT, flwT);
    k_conv<<<BB * 10, 512, 0, stream>>>(x, wt, cb, x2);
    k_lr_t<<<BB * 13, 512, 0, stream>>>(x2, tlwT, tlb, LT, Rt);
    k_att_t<<<BB * 13, 512, 0, stream>>>(LT, Rt, ta, tbias, x2, x3T);
    k_lr_f<<<BB * 16, 512, 0, stream>>>(x3T, flwT, flb, LT, Rt);
    k_att_f<<<BB * 16, 512, 0, stream>>>(LT, Rt, fa, fbias, x3T, fcw, tj);
    k_fc<<<BB, 128, 0, stream>>>(tj, emb, fcb, out);
}